// Round 1
// 2079.590 us; speedup vs baseline: 1.0107x; 1.0107x over previous
//
#include <hip/hip_runtime.h>
#include <math.h>
#include <stdint.h>

#define HID 256
#define NGRAPH 64
typedef unsigned short ushort_t;

typedef __attribute__((ext_vector_type(8))) short short8;
typedef __attribute__((ext_vector_type(4))) float f32x4;

// exact fp32 -> bf16 hi/lo split (RNE both)
__device__ __forceinline__ void split2(float v, ushort_t& h, ushort_t& l) {
  unsigned u = __float_as_uint(v);
  unsigned hr = u + 0x7FFFu + ((u >> 16) & 1u);
  h = (ushort_t)(hr >> 16);
  float hf = __uint_as_float(((unsigned)h) << 16);
  float r = v - hf;
  unsigned u2 = __float_as_uint(r);
  unsigned lr = u2 + 0x7FFFu + ((u2 >> 16) & 1u);
  l = (ushort_t)(lr >> 16);
}

#define GLDS(g, l) \
  __builtin_amdgcn_global_load_lds((const __attribute__((address_space(1))) void*)(g), \
                                   (__attribute__((address_space(3))) void*)(l), 16, 0, 0)

// ---------------- MFMA split-bf16 GEMM, fused N=512 ----------------
// A: [Mpad][Kpad] bf16 hi/lo. B: [512][Kpad] bf16 hi/lo (Wl^T rows 0-255, Wr^T 256-511).
// C: [M][512] fp32 = A*B^T (3-term split: hh + hl + lh)
// 2-phase double-buffered LDS pipeline (T3-minimum): stage(t+1) issued before
// ds_read+MFMA of t; one barrier per K-step. LDS slot swizzle: LDS slot c of
// row r holds global 16B-chunk c^(r&3) (pre-swizzled global source, linear LDS
// dest as required by global_load_lds); reads XOR the slot back.
__global__ __launch_bounds__(256) void mfma_gemm512_kernel(
    const ushort_t* __restrict__ Ah, const ushort_t* __restrict__ Al,
    const ushort_t* __restrict__ Bh, const ushort_t* __restrict__ Bl,
    float* __restrict__ C, int Mrows, int Kpad) {
  __shared__ ushort_t lA[2][2][128 * 32];  // [buf][hi/lo][row*32+k]
  __shared__ ushort_t lB[2][2][128 * 32];
  const int tid = threadIdx.x;

  // XCD-bijective block remap: original flat id f lands on XCD f%8; give each
  // XCD a contiguous chunk of tile-space so the 4 N-tiles sharing an A-tile
  // run consecutively on ONE XCD (A re-reads become L2 hits).
  const unsigned nwg = gridDim.x * gridDim.y;
  const unsigned flat = blockIdx.y * gridDim.x + blockIdx.x;
  const unsigned qq = nwg >> 3, rr = nwg & 7u;
  const unsigned xcd = flat & 7u, idx = flat >> 3;
  const unsigned swz =
      (xcd < rr ? xcd * (qq + 1u) : rr * (qq + 1u) + (xcd - rr) * qq) + idx;
  const int m0 = (int)(swz / gridDim.x) * 128;
  const int n0 = (int)(swz % gridDim.x) * 128;

  const int w = tid >> 6, lane = tid & 63;
  const int wm = (w >> 1) * 64, wn = (w & 1) * 64;
  const int col = lane & 15, quad = lane >> 4;

  f32x4 acc[4][4];
#pragma unroll
  for (int i = 0; i < 4; ++i)
#pragma unroll
    for (int j = 0; j < 4; ++j) acc[i][j] = (f32x4)(0.f);

  const int nkt = Kpad >> 5;

  // stage K-tile (kt element offset) into buffer s
#define STAGE512(kt_, s_)                                              \
  {                                                                    \
    _Pragma("unroll") for (int j = 0; j < 2; ++j) {                    \
      const int ch = tid + j * 256;                                    \
      const int r = ch >> 2;                                           \
      const int cs = (ch & 3) ^ (r & 3); /* pre-swizzled source slot */\
      const size_t goA = (size_t)(m0 + r) * Kpad + (kt_) + cs * 8;     \
      const size_t goB = (size_t)(n0 + r) * Kpad + (kt_) + cs * 8;     \
      GLDS(Ah + goA, &lA[s_][0][ch * 8]);                              \
      GLDS(Al + goA, &lA[s_][1][ch * 8]);                              \
      GLDS(Bh + goB, &lB[s_][0][ch * 8]);                              \
      GLDS(Bl + goB, &lB[s_][1][ch * 8]);                              \
    }                                                                  \
  }

  STAGE512(0, 0);
  __syncthreads();  // drains vmcnt(0): buf0 ready

  int cur = 0;
  for (int t = 0; t < nkt; ++t) {
    // issue next tile's loads first — HBM latency hides under ds_read+MFMA
    if (t + 1 < nkt) STAGE512((t + 1) << 5, cur ^ 1);

    short8 ah[4], al[4], bh[4], bl[4];
#pragma unroll
    for (int i = 0; i < 4; ++i) {
      const int ar = wm + i * 16 + col;
      const int sa = (quad ^ (ar & 3)) * 8;  // un-swizzle slot
      ah[i] = *(const short8*)&lA[cur][0][ar * 32 + sa];
      al[i] = *(const short8*)&lA[cur][1][ar * 32 + sa];
      const int br = wn + i * 16 + col;
      const int sb = (quad ^ (br & 3)) * 8;
      bh[i] = *(const short8*)&lB[cur][0][br * 32 + sb];
      bl[i] = *(const short8*)&lB[cur][1][br * 32 + sb];
    }
#pragma unroll
    for (int i = 0; i < 4; ++i)
#pragma unroll
      for (int j = 0; j < 4; ++j) {
        acc[i][j] = __builtin_amdgcn_mfma_f32_16x16x32_bf16(ah[i], bh[j], acc[i][j], 0, 0, 0);
        acc[i][j] = __builtin_amdgcn_mfma_f32_16x16x32_bf16(ah[i], bl[j], acc[i][j], 0, 0, 0);
        acc[i][j] = __builtin_amdgcn_mfma_f32_16x16x32_bf16(al[i], bh[j], acc[i][j], 0, 0, 0);
      }
    // __syncthreads drains this wave's lgkmcnt (ds_reads of buf cur done) and
    // vmcnt (next buf's global_load_lds landed) before anyone flips buffers.
    __syncthreads();
    cur ^= 1;
  }
#undef STAGE512

#pragma unroll
  for (int i = 0; i < 4; ++i) {
    const int r0 = m0 + wm + i * 16 + quad * 4;
#pragma unroll
    for (int j = 0; j < 4; ++j) {
      const int cc = n0 + wn + j * 16 + col;
#pragma unroll
      for (int r = 0; r < 4; ++r)
        if (r0 + r < Mrows) C[(size_t)(r0 + r) * 512 + cc] = acc[i][j][r];
    }
  }
}

// ---------------- attention GEMM (N=128) with fused tanh-dot scorer ----------------
// computes t = h@Wa1 per 128x128 tile, then s[m] = sum_c tanh(t[m][c]+ba1[c])*Wa2[c] + ba2
__global__ __launch_bounds__(256) void mfma_att_kernel(
    const ushort_t* __restrict__ Ah, const ushort_t* __restrict__ Al,
    const ushort_t* __restrict__ Bh, const ushort_t* __restrict__ Bl,
    const float* __restrict__ ba1, const float* __restrict__ Wa2,
    const float* __restrict__ ba2, float* __restrict__ S, int Mrows, int Kpad) {
  __shared__ ushort_t lAh[128 * 32];
  __shared__ ushort_t lAl[128 * 32];
  __shared__ ushort_t lBh[128 * 32];
  __shared__ ushort_t lBl[128 * 32];
  __shared__ float sat[128][2];
  const int tid = threadIdx.x;
  const int m0 = blockIdx.y * 128;
  const int w = tid >> 6, lane = tid & 63;
  const int wm = (w >> 1) * 64, wn = (w & 1) * 64;
  const int col = lane & 15, quad = lane >> 4;

  f32x4 acc[4][4];
#pragma unroll
  for (int i = 0; i < 4; ++i)
#pragma unroll
    for (int j = 0; j < 4; ++j) acc[i][j] = (f32x4)(0.f);

  for (int kt = 0; kt < Kpad; kt += 32) {
#pragma unroll
    for (int j = 0; j < 2; ++j) {
      const int ch = tid + j * 256;
      const int r = ch >> 2, c = ch & 3;
      const size_t goA = (size_t)(m0 + r) * Kpad + kt + c * 8;
      const size_t goB = (size_t)r * Kpad + kt + c * 8;
      GLDS(Ah + goA, &lAh[ch * 8]);
      GLDS(Al + goA, &lAl[ch * 8]);
      GLDS(Bh + goB, &lBh[ch * 8]);
      GLDS(Bl + goB, &lBl[ch * 8]);
    }
    __syncthreads();
    short8 ah[4], al[4], bh[4], bl[4];
#pragma unroll
    for (int i = 0; i < 4; ++i) {
      const int ar = wm + i * 16 + col;
      ah[i] = *(const short8*)&lAh[ar * 32 + quad * 8];
      al[i] = *(const short8*)&lAl[ar * 32 + quad * 8];
      const int br = wn + i * 16 + col;
      bh[i] = *(const short8*)&lBh[br * 32 + quad * 8];
      bl[i] = *(const short8*)&lBl[br * 32 + quad * 8];
    }
    __syncthreads();
#pragma unroll
    for (int i = 0; i < 4; ++i)
#pragma unroll
      for (int j = 0; j < 4; ++j) {
        acc[i][j] = __builtin_amdgcn_mfma_f32_16x16x32_bf16(ah[i], bh[j], acc[i][j], 0, 0, 0);
        acc[i][j] = __builtin_amdgcn_mfma_f32_16x16x32_bf16(ah[i], bl[j], acc[i][j], 0, 0, 0);
        acc[i][j] = __builtin_amdgcn_mfma_f32_16x16x32_bf16(al[i], bh[j], acc[i][j], 0, 0, 0);
      }
  }
  // epilogue: per-row tanh-dot
  float part[4][4];
#pragma unroll
  for (int i = 0; i < 4; ++i)
#pragma unroll
    for (int r = 0; r < 4; ++r) part[i][r] = 0.f;
#pragma unroll
  for (int j = 0; j < 4; ++j) {
    const int cc = wn + j * 16 + col;
    const float a1 = ba1[cc];
    const float w2 = Wa2[cc];
#pragma unroll
    for (int i = 0; i < 4; ++i)
#pragma unroll
      for (int r = 0; r < 4; ++r)
        part[i][r] += tanhf(acc[i][j][r] + a1) * w2;
  }
#pragma unroll
  for (int mask = 1; mask < 16; mask <<= 1)
#pragma unroll
    for (int i = 0; i < 4; ++i)
#pragma unroll
      for (int r = 0; r < 4; ++r) part[i][r] += __shfl_xor(part[i][r], mask, 64);
  if (col == 0) {
#pragma unroll
    for (int i = 0; i < 4; ++i)
#pragma unroll
      for (int r = 0; r < 4; ++r) sat[wm + i * 16 + quad * 4 + r][wn >> 6] = part[i][r];
  }
  __syncthreads();
  if (tid < 128) {
    const int gm = m0 + tid;
    if (gm < Mrows) S[gm] = sat[tid][0] + sat[tid][1] + ba2[0];
  }
}

// ---------------- conversions ----------------
__global__ __launch_bounds__(256) void convert_x_kernel(
    const float* __restrict__ x, int nrows,
    ushort_t* __restrict__ xh, ushort_t* __restrict__ xl, int K, int Kpad) {
  const int perRow = Kpad / 4;
  const int t = blockIdx.x * blockDim.x + threadIdx.x;
  if (t >= nrows * perRow) return;
  const int r = t / perRow, k0 = (t % perRow) * 4;
  const float* xr = x + (size_t)r * K;
  ushort_t h[4], l[4];
#pragma unroll
  for (int i = 0; i < 4; ++i) {
    const float v = (k0 + i < K) ? xr[k0 + i] : 0.f;
    split2(v, h[i], l[i]);
  }
  const size_t o = (size_t)r * Kpad + k0;
  *(ushort4*)(xh + o) = make_ushort4(h[0], h[1], h[2], h[3]);
  *(ushort4*)(xl + o) = make_ushort4(l[0], l[1], l[2], l[3]);
}

// fused transpose+split: rows n<256 from W1[k][n], n>=256 from W2[k][n-256]
__global__ void convert_wt_kernel(const float* __restrict__ W1, const float* __restrict__ W2,
                                  ushort_t* __restrict__ wth, ushort_t* __restrict__ wtl,
                                  int K, int Kpad, int ntot, int ld) {
  const int t = blockIdx.x * blockDim.x + threadIdx.x;
  if (t >= ntot * Kpad) return;
  const int n = t / Kpad, k = t % Kpad;
  float v = 0.f;
  if (k < K) v = (n < 256) ? W1[(size_t)k * ld + n] : W2[(size_t)k * ld + (n - 256)];
  ushort_t h, l;
  split2(v, h, l);
  wth[t] = h;
  wtl[t] = l;
}

// ---------------- CSR build ----------------
__global__ void deg_count_kernel(const int* __restrict__ dst, int* __restrict__ degi, int nE) {
  int e = blockIdx.x * blockDim.x + threadIdx.x;
  if (e < nE) atomicAdd(&degi[dst[e]], 1);
}

__global__ __launch_bounds__(1024) void scan_kernel(const int* __restrict__ degi,
                                                    int* __restrict__ rowptr, int M) {
  __shared__ int part[1024];
  const int t = threadIdx.x;
  const int chunk = (M + 1023) / 1024;
  const int b0 = min(t * chunk, M);
  const int b1 = min(b0 + chunk, M);
  int s = 0;
  for (int i = b0; i < b1; ++i) s += degi[i];
  part[t] = s;
  __syncthreads();
  for (int off = 1; off < 1024; off <<= 1) {
    int v = (t >= off) ? part[t - off] : 0;
    __syncthreads();
    part[t] += v;
    __syncthreads();
  }
  int ex = (t == 0) ? 0 : part[t - 1];
  for (int i = b0; i < b1; ++i) {
    rowptr[i] = ex;
    ex += degi[i];
  }
  if (t == 1023) rowptr[M] = part[1023];
}

__global__ void fill_kernel(const int* __restrict__ src, const int* __restrict__ dst,
                            int* __restrict__ fill, const int* __restrict__ rowptr,
                            int* __restrict__ csr_src, int nE) {
  int e = blockIdx.x * blockDim.x + threadIdx.x;
  if (e >= nE) return;
  const int d = dst[e];
  const int pos = rowptr[d] + atomicAdd(&fill[d], 1);
  csr_src[pos] = src[e];
}

// ---------------- fused gather-mean + bias + hr + BN stats ----------------
// gbuf: [M][512] (cols 0-255 = hl, 256-511 = hr)
#define GNB 64
__global__ __launch_bounds__(256) void gather_combine_kernel(
    const float* __restrict__ gbuf,
    const int* __restrict__ rowptr, const int* __restrict__ csr_src,
    const float* __restrict__ bl, float* preBN,
    float* __restrict__ bsum, float* __restrict__ bsumsq, int M) {
  __shared__ float lsum[4][HID];
  __shared__ float lsq[4][HID];
  const int w = threadIdx.x >> 6;
  const int lane = threadIdx.x & 63;
  const float4 blv = ((const float4*)bl)[lane];
  float4 s = make_float4(0.f, 0.f, 0.f, 0.f);
  float4 q = make_float4(0.f, 0.f, 0.f, 0.f);
  const int base = blockIdx.x * GNB;
  for (int it = 0; it < GNB / 4; ++it) {
    const int n = base + it * 4 + w;
    if (n < M) {
      const int e0 = rowptr[n], e1 = rowptr[n + 1];
      float4 acc = make_float4(0.f, 0.f, 0.f, 0.f);
      for (int e = e0; e < e1; ++e) {
        const int sn = csr_src[e];
        const float4 v = ((const float4*)(gbuf + (size_t)sn * 512))[lane];
        acc.x += v.x; acc.y += v.y; acc.z += v.z; acc.w += v.w;
      }
      const float rd = 1.0f / fmaxf((float)(e1 - e0), 1.0f);
      const float4 hv = ((const float4*)(gbuf + (size_t)n * 512 + 256))[lane];
      float4 o;
      o.x = fmaf(acc.x, rd, blv.x + hv.x);
      o.y = fmaf(acc.y, rd, blv.y + hv.y);
      o.z = fmaf(acc.z, rd, blv.z + hv.z);
      o.w = fmaf(acc.w, rd, blv.w + hv.w);
      ((float4*)(preBN + (size_t)n * HID))[lane] = o;
      s.x += o.x; s.y += o.y; s.z += o.z; s.w += o.w;
      q.x = fmaf(o.x, o.x, q.x); q.y = fmaf(o.y, o.y, q.y);
      q.z = fmaf(o.z, o.z, q.z); q.w = fmaf(o.w, o.w, q.w);
    }
  }
  *(float4*)&lsum[w][lane * 4] = s;
  *(float4*)&lsq[w][lane * 4] = q;
  __syncthreads();
  const int c = threadIdx.x;
  const float ts = lsum[0][c] + lsum[1][c] + lsum[2][c] + lsum[3][c];
  const float tq = lsq[0][c] + lsq[1][c] + lsq[2][c] + lsq[3][c];
  atomicAdd(&bsum[c], ts);
  atomicAdd(&bsumsq[c], tq);
}

// BN(scale/shift recomputed per block) + ReLU -> bf16 split (+ optional fp32)
__global__ __launch_bounds__(256) void bn_apply_relu_convert_kernel(
    const float* __restrict__ preBN, const float* __restrict__ bsum,
    const float* __restrict__ bsumsq, const float* __restrict__ g, const float* __restrict__ b,
    ushort_t* __restrict__ hh, ushort_t* __restrict__ hl, float* __restrict__ hout,
    int M, int n4) {
  __shared__ float s_sc[HID], s_sh[HID];
  {
    const int c = threadIdx.x;
    const float inv = 1.0f / (float)M;
    const float mean = bsum[c] * inv;
    const float var = bsumsq[c] * inv - mean * mean;
    const float sc = g[c] * rsqrtf(var + 1e-5f);
    s_sc[c] = sc;
    s_sh[c] = b[c] - mean * sc;
  }
  __syncthreads();
  const int i = blockIdx.x * blockDim.x + threadIdx.x;
  if (i >= n4) return;
  const int c0 = (i & (HID / 4 - 1)) * 4;
  const float4 v = ((const float4*)preBN)[i];
  float o[4];
  o[0] = fmaxf(fmaf(v.x, s_sc[c0 + 0], s_sh[c0 + 0]), 0.f);
  o[1] = fmaxf(fmaf(v.y, s_sc[c0 + 1], s_sh[c0 + 1]), 0.f);
  o[2] = fmaxf(fmaf(v.z, s_sc[c0 + 2], s_sh[c0 + 2]), 0.f);
  o[3] = fmaxf(fmaf(v.w, s_sc[c0 + 3], s_sh[c0 + 3]), 0.f);
  ushort_t h[4], l[4];
#pragma unroll
  for (int k = 0; k < 4; ++k) split2(o[k], h[k], l[k]);
  ((ushort4*)hh)[i] = make_ushort4(h[0], h[1], h[2], h[3]);
  ((ushort4*)hl)[i] = make_ushort4(l[0], l[1], l[2], l[3]);
  if (hout) ((float4*)hout)[i] = make_float4(o[0], o[1], o[2], o[3]);
}

// ---------------- softmax over graphs ----------------
__device__ __forceinline__ unsigned fflip(float f) {
  unsigned u = __float_as_uint(f);
  return (u & 0x80000000u) ? ~u : (u | 0x80000000u);
}
__device__ __forceinline__ float funflip(unsigned u) {
  return __uint_as_float((u & 0x80000000u) ? (u ^ 0x80000000u) : ~u);
}

__global__ void seg_max_kernel(const float* __restrict__ s, const int* __restrict__ batch,
                               unsigned* __restrict__ gmax, int M) {
  __shared__ unsigned lmax[NGRAPH];
  if (threadIdx.x < NGRAPH) lmax[threadIdx.x] = 0u;
  __syncthreads();
  for (int i = blockIdx.x * blockDim.x + threadIdx.x; i < M; i += gridDim.x * blockDim.x)
    atomicMax(&lmax[batch[i]], fflip(s[i]));
  __syncthreads();
  if (threadIdx.x < NGRAPH && lmax[threadIdx.x] != 0u) atomicMax(&gmax[threadIdx.x], lmax[threadIdx.x]);
}

__global__ void seg_expsum_kernel(const float* __restrict__ s, const int* __restrict__ batch,
                                  const unsigned* __restrict__ gmax, float* __restrict__ e,
                                  float* __restrict__ denom, int M) {
  __shared__ float ld[NGRAPH];
  if (threadIdx.x < NGRAPH) ld[threadIdx.x] = 0.f;
  __syncthreads();
  for (int i = blockIdx.x * blockDim.x + threadIdx.x; i < M; i += gridDim.x * blockDim.x) {
    const int b = batch[i];
    const float v = expf(s[i] - funflip(gmax[b]));
    e[i] = v;
    atomicAdd(&ld[b], v);
  }
  __syncthreads();
  if (threadIdx.x < NGRAPH && ld[threadIdx.x] != 0.f) atomicAdd(&denom[threadIdx.x], ld[threadIdx.x]);
}

#define PNB 16
__global__ __launch_bounds__(256) void pool_kernel(
    const float* __restrict__ h, const float* __restrict__ e, const float* __restrict__ denom,
    const int* __restrict__ batch, float* __restrict__ pooled, int M) {
  const int wid = (blockIdx.x * blockDim.x + threadIdx.x) >> 6;
  const int lane = threadIdx.x & 63;
  const int n0 = wid * PNB;
  if (n0 >= M) return;
  const int n1 = min(n0 + PNB, M);
  float4 acc = make_float4(0.f, 0.f, 0.f, 0.f);
  int cur = batch[n0];
  for (int n = n0; n < n1; ++n) {
    const int b = batch[n];
    if (b != cur) {
      float* o = pooled + (size_t)cur * HID + lane * 4;
      atomicAdd(o + 0, acc.x); atomicAdd(o + 1, acc.y);
      atomicAdd(o + 2, acc.z); atomicAdd(o + 3, acc.w);
      acc = make_float4(0.f, 0.f, 0.f, 0.f);
      cur = b;
    }
    const float w = e[n] / denom[b];
    const float4 v = ((const float4*)(h + (size_t)n * HID))[lane];
    acc.x = fmaf(v.x, w, acc.x); acc.y = fmaf(v.y, w, acc.y);
    acc.z = fmaf(v.z, w, acc.z); acc.w = fmaf(v.w, w, acc.w);
  }
  float* o = pooled + (size_t)cur * HID + lane * 4;
  atomicAdd(o + 0, acc.x); atomicAdd(o + 1, acc.y);
  atomicAdd(o + 2, acc.z); atomicAdd(o + 3, acc.w);
}

__global__ __launch_bounds__(128) void classifier_kernel(
    const float* __restrict__ pooled, const float* __restrict__ Wc1, const float* __restrict__ bc1,
    const float* __restrict__ Wc2, const float* __restrict__ bc2, float* __restrict__ out) {
  __shared__ float red[128];
  const int g = blockIdx.x;
  const int j = threadIdx.x;
  float acc = bc1[j];
  const float* p = pooled + (size_t)g * HID;
  for (int c = 0; c < HID; ++c) acc = fmaf(p[c], Wc1[c * 128 + j], acc);
  red[j] = fmaxf(acc, 0.f) * Wc2[j];
  __syncthreads();
  for (int off = 64; off > 0; off >>= 1) {
    if (j < off) red[j] += red[j + off];
    __syncthreads();
  }
  if (j == 0) out[g] = red[0] + bc2[0];
}

extern "C" void kernel_launch(void* const* d_in, const int* in_sizes, int n_in,
                              void* d_out, int out_size, void* d_ws, size_t ws_size,
                              hipStream_t stream) {
  const float* x = (const float*)d_in[0];
  const int* edge = (const int*)d_in[1];
  const int* batch = (const int*)d_in[2];
  const int M = in_sizes[2];
  const int nE = in_sizes[1] / 2;
  const int IN_DIM = in_sizes[0] / M;  // 771
  const int* src = edge;
  const int* dst = edge + nE;

  const int Mpad = ((M + 127) / 128) * 128;
  const int KP0 = ((IN_DIM + 31) / 32) * 32;  // 800
  const int mblocks = (M + 127) / 128;

  float* ws = (float*)d_ws;
  float* gbuf = ws;                                    // [M][512]
  float* pbuf = gbuf + (size_t)M * 512;                // [M][256]
  float* h32 = pbuf + (size_t)M * HID;                 // [M][256]
  float* ssc = h32 + (size_t)M * HID;                  // M
  float* ew = ssc + M;                                 // M
  float* bsumA = ew + M;                               // 3 layers x (256 sum + 256 sq)
  unsigned* gmax = (unsigned*)(bsumA + 6 * HID);       // 64
  float* denom = (float*)(gmax + NGRAPH);              // 64
  float* pooled = denom + NGRAPH;                      // 64*256
  int* degi = (int*)(pooled + (size_t)NGRAPH * HID);   // M
  int* filla = degi + M;                               // M
  int* rowptr = filla + M;                             // M+1
  int* csr_src = rowptr + M + 1;                       // nE

  ushort_t* wp = (ushort_t*)(((uintptr_t)(csr_src + nE) + 15) & ~(uintptr_t)15);
  ushort_t* w0h = wp;                 ushort_t* w0l = w0h + (size_t)512 * KP0;
  ushort_t* w1h = w0l + (size_t)512 * KP0;  ushort_t* w1l = w1h + (size_t)512 * HID;
  ushort_t* w2h = w1l + (size_t)512 * HID;  ushort_t* w2l = w2h + (size_t)512 * HID;
  ushort_t* wah = w2l + (size_t)512 * HID;  ushort_t* wal = wah + (size_t)128 * HID;
  ushort_t* cvh = (ushort_t*)(((uintptr_t)(wal + (size_t)128 * HID) + 15) & ~(uintptr_t)15);
  ushort_t* cvl = cvh + (size_t)Mpad * KP0;

  // ---- CSR build ----
  hipMemsetAsync(degi, 0, (size_t)(2 * M) * sizeof(int), stream);
  deg_count_kernel<<<(nE + 255) / 256, 256, 0, stream>>>(dst, degi, nE);
  scan_kernel<<<1, 1024, 0, stream>>>(degi, rowptr, M);
  fill_kernel<<<(nE + 255) / 256, 256, 0, stream>>>(src, dst, filla, rowptr, csr_src, nE);
  // one memset for all small accumulators: bsumA(1536) + gmax(64) + denom(64) + pooled(16384)
  hipMemsetAsync(bsumA, 0, (size_t)(6 * HID + 2 * NGRAPH + NGRAPH * HID) * 4, stream);

  // ---- weight transpose + split (fused Wl||Wr per layer) ----
  {
    const int nt0 = 512 * KP0;
    convert_wt_kernel<<<(nt0 + 255) / 256, 256, 0, stream>>>(
        (const float*)d_in[3], (const float*)d_in[5], w0h, w0l, IN_DIM, KP0, 512, HID);
    const int nt1 = 512 * HID;
    convert_wt_kernel<<<(nt1 + 255) / 256, 256, 0, stream>>>(
        (const float*)d_in[8], (const float*)d_in[10], w1h, w1l, HID, HID, 512, HID);
    convert_wt_kernel<<<(nt1 + 255) / 256, 256, 0, stream>>>(
        (const float*)d_in[13], (const float*)d_in[15], w2h, w2l, HID, HID, 512, HID);
    convert_wt_kernel<<<(128 * HID + 255) / 256, 256, 0, stream>>>(
        (const float*)d_in[18], nullptr, wah, wal, HID, HID, 128, 128);
  }

  // layer-0 input split
  {
    const int nt = M * (KP0 / 4);
    convert_x_kernel<<<(nt + 255) / 256, 256, 0, stream>>>(x, M, cvh, cvl, IN_DIM, KP0);
  }

  const int n4 = (int)((size_t)M * HID / 4);
  const ushort_t* WH[3] = {w0h, w1h, w2h};
  const ushort_t* WL[3] = {w0l, w1l, w2l};
  for (int l = 0; l < 3; ++l) {
    const int KP = (l == 0) ? KP0 : HID;
    const float* bl = (const float*)d_in[3 + l * 5 + 1];
    const float* gg = (const float*)d_in[3 + l * 5 + 3];
    const float* bb = (const float*)d_in[3 + l * 5 + 4];
    float* bsum = bsumA + l * 512;
    float* bsumsq = bsum + HID;

    dim3 g(4, mblocks);
    mfma_gemm512_kernel<<<g, 256, 0, stream>>>(cvh, cvl, WH[l], WL[l], gbuf, M, KP);
    gather_combine_kernel<<<(M + GNB - 1) / GNB, 256, 0, stream>>>(
        gbuf, rowptr, csr_src, bl, pbuf, bsum, bsumsq, M);
    // overwrite cvh/cvl with next layer's split ([Mpad][256] fits in [Mpad][800] region)
    bn_apply_relu_convert_kernel<<<(n4 + 255) / 256, 256, 0, stream>>>(
        pbuf, bsum, bsumsq, gg, bb, cvh, cvl, (l == 2) ? h32 : nullptr, M, n4);
  }

  // attention scores (GEMM + fused tanh-dot epilogue)
  {
    dim3 g(1, mblocks);
    mfma_att_kernel<<<g, 256, 0, stream>>>(
        cvh, cvl, wah, wal, (const float*)d_in[19], (const float*)d_in[20],
        (const float*)d_in[21], ssc, M, HID);
  }
  seg_max_kernel<<<512, 256, 0, stream>>>(ssc, batch, gmax, M);
  seg_expsum_kernel<<<512, 256, 0, stream>>>(ssc, batch, gmax, ew, denom, M);
  {
    const int nwaves = (M + PNB - 1) / PNB;
    pool_kernel<<<(nwaves * 64 + 255) / 256, 256, 0, stream>>>(h32, ew, denom, batch, pooled, M);
  }
  classifier_kernel<<<NGRAPH, 128, 0, stream>>>(
      pooled, (const float*)d_in[22], (const float*)d_in[23],
      (const float*)d_in[24], (const float*)d_in[25], (float*)d_out);
}

// Round 2
// 2050.460 us; speedup vs baseline: 1.0251x; 1.0142x over previous
//
#include <hip/hip_runtime.h>
#include <math.h>
#include <stdint.h>

#define HID 256
#define NGRAPH 64
typedef unsigned short ushort_t;

typedef __attribute__((ext_vector_type(8))) short short8;
typedef __attribute__((ext_vector_type(4))) float f32x4;

// exact fp32 -> bf16 hi/lo split (RNE both)
__device__ __forceinline__ void split2(float v, ushort_t& h, ushort_t& l) {
  unsigned u = __float_as_uint(v);
  unsigned hr = u + 0x7FFFu + ((u >> 16) & 1u);
  h = (ushort_t)(hr >> 16);
  float hf = __uint_as_float(((unsigned)h) << 16);
  float r = v - hf;
  unsigned u2 = __float_as_uint(r);
  unsigned lr = u2 + 0x7FFFu + ((u2 >> 16) & 1u);
  l = (ushort_t)(lr >> 16);
}

#define GLDS(g, l) \
  __builtin_amdgcn_global_load_lds((const __attribute__((address_space(1))) void*)(g), \
                                   (__attribute__((address_space(3))) void*)(l), 16, 0, 0)

// ---------------- MFMA split-bf16 GEMM, fused N=512 ----------------
// A: [Mpad][Kpad] bf16 hi/lo. B: [512][Kpad] bf16 hi/lo (Wl^T rows 0-255, Wr^T 256-511).
// C: [M][512] fp32 = A*B^T (3-term split: hh + hl + lh)
//
// 256x256 tile, 8 waves (2M x 4N), BK=32, 2 LDS buffers (128 KiB), depth-2
// prefetch with COUNTED vmcnt across raw barriers (T3+T4): loads for tile t+1
// stay in flight through tile t's compute; vmcnt never drains to 0 in-loop.
// LDS bank swizzle: slot s of row r holds global 16B-chunk s^((r>>1)&3),
// applied on the GLOBAL source address (global_load_lds dest must be linear);
// read side XORs the slot back -> bank-group (4r+s)&7 is a permutation over
// 8 rows => 2-way conflict only (free).
__global__ __launch_bounds__(512, 2) void mfma_gemm512_kernel(
    const ushort_t* __restrict__ Ah, const ushort_t* __restrict__ Al,
    const ushort_t* __restrict__ Bh, const ushort_t* __restrict__ Bl,
    float* __restrict__ C, int Mrows, int Kpad) {
  __shared__ ushort_t lA[2][2][256 * 32];  // [buf][hi/lo][row*32 + slot*8 + e]
  __shared__ ushort_t lB[2][2][256 * 32];
  const int tid = threadIdx.x;

  // XCD-bijective block remap (chunked): the 2 N-tiles sharing an A-tile run
  // consecutively on ONE XCD -> A re-reads are L2 hits.
  const unsigned nwg = gridDim.x * gridDim.y;
  const unsigned flat = blockIdx.y * gridDim.x + blockIdx.x;
  const unsigned qq = nwg >> 3, rr = nwg & 7u;
  const unsigned xcd = flat & 7u, idx = flat >> 3;
  const unsigned swz =
      (xcd < rr ? xcd * (qq + 1u) : rr * (qq + 1u) + (xcd - rr) * qq) + idx;
  const int m0 = (int)(swz / gridDim.x) * 256;
  const int n0 = (int)(swz % gridDim.x) * 256;

  const int w = tid >> 6, lane = tid & 63;
  const int wm = (w >> 2) * 128, wn = (w & 3) * 64;  // wave tile: 128x64
  const int col = lane & 15, quad = lane >> 4;

  f32x4 acc[8][4];
#pragma unroll
  for (int i = 0; i < 8; ++i)
#pragma unroll
    for (int j = 0; j < 4; ++j) acc[i][j] = (f32x4)(0.f);

  const int nkt = Kpad >> 5;

  // staging map: thread handles LDS chunks tid and tid+512 of each 1024-chunk
  // tile (chunk = row*4+slot). Global source chunk g = slot ^ ((row>>1)&3);
  // rows r0s and r0s+128 share the same g (128 = 0 mod 4 after >>1 &3).
  const int r0s = tid >> 2;
  const int g_ = (tid & 3) ^ ((r0s >> 1) & 3);

#define STAGE256(kt_, s_)                                         \
  {                                                               \
    const size_t kb = (size_t)(kt_) + g_ * 8;                     \
    const size_t gA0 = (size_t)(m0 + r0s) * Kpad + kb;            \
    const size_t gA1 = (size_t)(m0 + r0s + 128) * Kpad + kb;      \
    const size_t gB0 = (size_t)(n0 + r0s) * Kpad + kb;            \
    const size_t gB1 = (size_t)(n0 + r0s + 128) * Kpad + kb;      \
    GLDS(Ah + gA0, &lA[s_][0][tid * 8]);                          \
    GLDS(Ah + gA1, &lA[s_][0][(tid + 512) * 8]);                  \
    GLDS(Al + gA0, &lA[s_][1][tid * 8]);                          \
    GLDS(Al + gA1, &lA[s_][1][(tid + 512) * 8]);                  \
    GLDS(Bh + gB0, &lB[s_][0][tid * 8]);                          \
    GLDS(Bh + gB1, &lB[s_][0][(tid + 512) * 8]);                  \
    GLDS(Bl + gB0, &lB[s_][1][tid * 8]);                          \
    GLDS(Bl + gB1, &lB[s_][1][(tid + 512) * 8]);                  \
  }

  // prologue: stage tiles 0 and 1; wait only for tile 0 (8 newest stay in flight)
  STAGE256(0, 0);
  if (nkt > 1) {
    STAGE256(32, 1);
    asm volatile("s_waitcnt vmcnt(8)\ns_barrier" ::: "memory");
  } else {
    asm volatile("s_waitcnt vmcnt(0)\ns_barrier" ::: "memory");
  }

#define LDA2(q_, ph_, pl_)                                        \
  {                                                               \
    const int arA = wm + (q_) * 32 + col;                         \
    const int arB = arA + 16;                                     \
    const int sA = (quad ^ ((arA >> 1) & 3)) * 8;                 \
    const int sB = (quad ^ ((arB >> 1) & 3)) * 8;                 \
    ph_[0] = *(const short8*)&lA[c][0][arA * 32 + sA];            \
    pl_[0] = *(const short8*)&lA[c][1][arA * 32 + sA];            \
    ph_[1] = *(const short8*)&lA[c][0][arB * 32 + sB];            \
    pl_[1] = *(const short8*)&lA[c][1][arB * 32 + sB];            \
  }

  for (int t = 0; t < nkt; ++t) {
    const int c = t & 1;
    // B fragments for all 4 n-tiles (shared across the 8 m-tiles)
    short8 Bh_[4], Bl_[4];
#pragma unroll
    for (int j = 0; j < 4; ++j) {
      const int br = wn + j * 16 + col;
      const int s = (quad ^ ((br >> 1) & 3)) * 8;
      Bh_[j] = *(const short8*)&lB[c][0][br * 32 + s];
      Bl_[j] = *(const short8*)&lB[c][1][br * 32 + s];
    }
    // A fragments pipelined in pairs of m-tiles (static 2-slot, rule #20 safe)
    short8 pAh[2][2], pAl[2][2];
    LDA2(0, pAh[0], pAl[0]);
#pragma unroll
    for (int p = 0; p < 4; ++p) {
      if (p < 3) LDA2(p + 1, pAh[(p + 1) & 1], pAl[(p + 1) & 1]);
      __builtin_amdgcn_s_setprio(1);
#pragma unroll
      for (int ii = 0; ii < 2; ++ii) {
        const int i = 2 * p + ii;
#pragma unroll
        for (int j = 0; j < 4; ++j) {
          acc[i][j] = __builtin_amdgcn_mfma_f32_16x16x32_bf16(pAh[p & 1][ii], Bh_[j], acc[i][j], 0, 0, 0);
          acc[i][j] = __builtin_amdgcn_mfma_f32_16x16x32_bf16(pAh[p & 1][ii], Bl_[j], acc[i][j], 0, 0, 0);
          acc[i][j] = __builtin_amdgcn_mfma_f32_16x16x32_bf16(pAl[p & 1][ii], Bh_[j], acc[i][j], 0, 0, 0);
        }
      }
      __builtin_amdgcn_s_setprio(0);
    }
    if (t + 1 < nkt) {
      // release buf c: this wave's ds_reads done + all waves past this point
      asm volatile("s_waitcnt lgkmcnt(0)\ns_barrier" ::: "memory");
      if (t + 2 < nkt) {
        STAGE256((t + 2) << 5, c);
        // ready barrier: tile t+1's 8 loads (oldest) done; t+2's 8 stay in flight
        asm volatile("s_waitcnt vmcnt(8)\ns_barrier" ::: "memory");
      } else {
        asm volatile("s_waitcnt vmcnt(0)\ns_barrier" ::: "memory");
      }
    }
  }
#undef STAGE256
#undef LDA2

#pragma unroll
  for (int i = 0; i < 8; ++i) {
    const int r0 = m0 + wm + i * 16 + quad * 4;
#pragma unroll
    for (int j = 0; j < 4; ++j) {
      const int cc = n0 + wn + j * 16 + col;
#pragma unroll
      for (int r = 0; r < 4; ++r)
        if (r0 + r < Mrows) C[(size_t)(r0 + r) * 512 + cc] = acc[i][j][r];
    }
  }
}

// ---------------- attention GEMM (N=128) with fused tanh-dot scorer ----------------
// computes t = h@Wa1 per 128x128 tile, then s[m] = sum_c tanh(t[m][c]+ba1[c])*Wa2[c] + ba2
__global__ __launch_bounds__(256) void mfma_att_kernel(
    const ushort_t* __restrict__ Ah, const ushort_t* __restrict__ Al,
    const ushort_t* __restrict__ Bh, const ushort_t* __restrict__ Bl,
    const float* __restrict__ ba1, const float* __restrict__ Wa2,
    const float* __restrict__ ba2, float* __restrict__ S, int Mrows, int Kpad) {
  __shared__ ushort_t lAh[128 * 32];
  __shared__ ushort_t lAl[128 * 32];
  __shared__ ushort_t lBh[128 * 32];
  __shared__ ushort_t lBl[128 * 32];
  __shared__ float sat[128][2];
  const int tid = threadIdx.x;
  const int m0 = blockIdx.y * 128;
  const int w = tid >> 6, lane = tid & 63;
  const int wm = (w >> 1) * 64, wn = (w & 1) * 64;
  const int col = lane & 15, quad = lane >> 4;

  f32x4 acc[4][4];
#pragma unroll
  for (int i = 0; i < 4; ++i)
#pragma unroll
    for (int j = 0; j < 4; ++j) acc[i][j] = (f32x4)(0.f);

  for (int kt = 0; kt < Kpad; kt += 32) {
#pragma unroll
    for (int j = 0; j < 2; ++j) {
      const int ch = tid + j * 256;
      const int r = ch >> 2, c = ch & 3;
      const size_t goA = (size_t)(m0 + r) * Kpad + kt + c * 8;
      const size_t goB = (size_t)r * Kpad + kt + c * 8;
      GLDS(Ah + goA, &lAh[ch * 8]);
      GLDS(Al + goA, &lAl[ch * 8]);
      GLDS(Bh + goB, &lBh[ch * 8]);
      GLDS(Bl + goB, &lBl[ch * 8]);
    }
    __syncthreads();
    short8 ah[4], al[4], bh[4], bl[4];
#pragma unroll
    for (int i = 0; i < 4; ++i) {
      const int ar = wm + i * 16 + col;
      ah[i] = *(const short8*)&lAh[ar * 32 + quad * 8];
      al[i] = *(const short8*)&lAl[ar * 32 + quad * 8];
      const int br = wn + i * 16 + col;
      bh[i] = *(const short8*)&lBh[br * 32 + quad * 8];
      bl[i] = *(const short8*)&lBl[br * 32 + quad * 8];
    }
    __syncthreads();
#pragma unroll
    for (int i = 0; i < 4; ++i)
#pragma unroll
      for (int j = 0; j < 4; ++j) {
        acc[i][j] = __builtin_amdgcn_mfma_f32_16x16x32_bf16(ah[i], bh[j], acc[i][j], 0, 0, 0);
        acc[i][j] = __builtin_amdgcn_mfma_f32_16x16x32_bf16(ah[i], bl[j], acc[i][j], 0, 0, 0);
        acc[i][j] = __builtin_amdgcn_mfma_f32_16x16x32_bf16(al[i], bh[j], acc[i][j], 0, 0, 0);
      }
  }
  // epilogue: per-row tanh-dot
  float part[4][4];
#pragma unroll
  for (int i = 0; i < 4; ++i)
#pragma unroll
    for (int r = 0; r < 4; ++r) part[i][r] = 0.f;
#pragma unroll
  for (int j = 0; j < 4; ++j) {
    const int cc = wn + j * 16 + col;
    const float a1 = ba1[cc];
    const float w2 = Wa2[cc];
#pragma unroll
    for (int i = 0; i < 4; ++i)
#pragma unroll
      for (int r = 0; r < 4; ++r)
        part[i][r] += tanhf(acc[i][j][r] + a1) * w2;
  }
#pragma unroll
  for (int mask = 1; mask < 16; mask <<= 1)
#pragma unroll
    for (int i = 0; i < 4; ++i)
#pragma unroll
      for (int r = 0; r < 4; ++r) part[i][r] += __shfl_xor(part[i][r], mask, 64);
  if (col == 0) {
#pragma unroll
    for (int i = 0; i < 4; ++i)
#pragma unroll
      for (int r = 0; r < 4; ++r) sat[wm + i * 16 + quad * 4 + r][wn >> 6] = part[i][r];
  }
  __syncthreads();
  if (tid < 128) {
    const int gm = m0 + tid;
    if (gm < Mrows) S[gm] = sat[tid][0] + sat[tid][1] + ba2[0];
  }
}

// ---------------- conversions ----------------
__global__ __launch_bounds__(256) void convert_x_kernel(
    const float* __restrict__ x, int nrows,
    ushort_t* __restrict__ xh, ushort_t* __restrict__ xl, int K, int Kpad) {
  const int perRow = Kpad / 4;
  const int t = blockIdx.x * blockDim.x + threadIdx.x;
  if (t >= nrows * perRow) return;
  const int r = t / perRow, k0 = (t % perRow) * 4;
  const float* xr = x + (size_t)r * K;
  ushort_t h[4], l[4];
#pragma unroll
  for (int i = 0; i < 4; ++i) {
    const float v = (k0 + i < K) ? xr[k0 + i] : 0.f;
    split2(v, h[i], l[i]);
  }
  const size_t o = (size_t)r * Kpad + k0;
  *(ushort4*)(xh + o) = make_ushort4(h[0], h[1], h[2], h[3]);
  *(ushort4*)(xl + o) = make_ushort4(l[0], l[1], l[2], l[3]);
}

// fused transpose+split: rows n<256 from W1[k][n], n>=256 from W2[k][n-256]
__global__ void convert_wt_kernel(const float* __restrict__ W1, const float* __restrict__ W2,
                                  ushort_t* __restrict__ wth, ushort_t* __restrict__ wtl,
                                  int K, int Kpad, int ntot, int ld) {
  const int t = blockIdx.x * blockDim.x + threadIdx.x;
  if (t >= ntot * Kpad) return;
  const int n = t / Kpad, k = t % Kpad;
  float v = 0.f;
  if (k < K) v = (n < 256) ? W1[(size_t)k * ld + n] : W2[(size_t)k * ld + (n - 256)];
  ushort_t h, l;
  split2(v, h, l);
  wth[t] = h;
  wtl[t] = l;
}

// ---------------- CSR build ----------------
__global__ void deg_count_kernel(const int* __restrict__ dst, int* __restrict__ degi, int nE) {
  int e = blockIdx.x * blockDim.x + threadIdx.x;
  if (e < nE) atomicAdd(&degi[dst[e]], 1);
}

__global__ __launch_bounds__(1024) void scan_kernel(const int* __restrict__ degi,
                                                    int* __restrict__ rowptr, int M) {
  __shared__ int part[1024];
  const int t = threadIdx.x;
  const int chunk = (M + 1023) / 1024;
  const int b0 = min(t * chunk, M);
  const int b1 = min(b0 + chunk, M);
  int s = 0;
  for (int i = b0; i < b1; ++i) s += degi[i];
  part[t] = s;
  __syncthreads();
  for (int off = 1; off < 1024; off <<= 1) {
    int v = (t >= off) ? part[t - off] : 0;
    __syncthreads();
    part[t] += v;
    __syncthreads();
  }
  int ex = (t == 0) ? 0 : part[t - 1];
  for (int i = b0; i < b1; ++i) {
    rowptr[i] = ex;
    ex += degi[i];
  }
  if (t == 1023) rowptr[M] = part[1023];
}

__global__ void fill_kernel(const int* __restrict__ src, const int* __restrict__ dst,
                            int* __restrict__ fill, const int* __restrict__ rowptr,
                            int* __restrict__ csr_src, int nE) {
  int e = blockIdx.x * blockDim.x + threadIdx.x;
  if (e >= nE) return;
  const int d = dst[e];
  const int pos = rowptr[d] + atomicAdd(&fill[d], 1);
  csr_src[pos] = src[e];
}

// ---------------- fused gather-mean + bias + hr + BN stats ----------------
// gbuf: [M][512] (cols 0-255 = hl, 256-511 = hr)
#define GNB 64
__global__ __launch_bounds__(256) void gather_combine_kernel(
    const float* __restrict__ gbuf,
    const int* __restrict__ rowptr, const int* __restrict__ csr_src,
    const float* __restrict__ bl, float* preBN,
    float* __restrict__ bsum, float* __restrict__ bsumsq, int M) {
  __shared__ float lsum[4][HID];
  __shared__ float lsq[4][HID];
  const int w = threadIdx.x >> 6;
  const int lane = threadIdx.x & 63;
  const float4 blv = ((const float4*)bl)[lane];
  float4 s = make_float4(0.f, 0.f, 0.f, 0.f);
  float4 q = make_float4(0.f, 0.f, 0.f, 0.f);
  const int base = blockIdx.x * GNB;
  for (int it = 0; it < GNB / 4; ++it) {
    const int n = base + it * 4 + w;
    if (n < M) {
      const int e0 = rowptr[n], e1 = rowptr[n + 1];
      float4 acc = make_float4(0.f, 0.f, 0.f, 0.f);
      for (int e = e0; e < e1; ++e) {
        const int sn = csr_src[e];
        const float4 v = ((const float4*)(gbuf + (size_t)sn * 512))[lane];
        acc.x += v.x; acc.y += v.y; acc.z += v.z; acc.w += v.w;
      }
      const float rd = 1.0f / fmaxf((float)(e1 - e0), 1.0f);
      const float4 hv = ((const float4*)(gbuf + (size_t)n * 512 + 256))[lane];
      float4 o;
      o.x = fmaf(acc.x, rd, blv.x + hv.x);
      o.y = fmaf(acc.y, rd, blv.y + hv.y);
      o.z = fmaf(acc.z, rd, blv.z + hv.z);
      o.w = fmaf(acc.w, rd, blv.w + hv.w);
      ((float4*)(preBN + (size_t)n * HID))[lane] = o;
      s.x += o.x; s.y += o.y; s.z += o.z; s.w += o.w;
      q.x = fmaf(o.x, o.x, q.x); q.y = fmaf(o.y, o.y, q.y);
      q.z = fmaf(o.z, o.z, q.z); q.w = fmaf(o.w, o.w, q.w);
    }
  }
  *(float4*)&lsum[w][lane * 4] = s;
  *(float4*)&lsq[w][lane * 4] = q;
  __syncthreads();
  const int c = threadIdx.x;
  const float ts = lsum[0][c] + lsum[1][c] + lsum[2][c] + lsum[3][c];
  const float tq = lsq[0][c] + lsq[1][c] + lsq[2][c] + lsq[3][c];
  atomicAdd(&bsum[c], ts);
  atomicAdd(&bsumsq[c], tq);
}

// BN(scale/shift recomputed per block) + ReLU -> bf16 split (+ optional fp32)
__global__ __launch_bounds__(256) void bn_apply_relu_convert_kernel(
    const float* __restrict__ preBN, const float* __restrict__ bsum,
    const float* __restrict__ bsumsq, const float* __restrict__ g, const float* __restrict__ b,
    ushort_t* __restrict__ hh, ushort_t* __restrict__ hl, float* __restrict__ hout,
    int M, int n4) {
  __shared__ float s_sc[HID], s_sh[HID];
  {
    const int c = threadIdx.x;
    const float inv = 1.0f / (float)M;
    const float mean = bsum[c] * inv;
    const float var = bsumsq[c] * inv - mean * mean;
    const float sc = g[c] * rsqrtf(var + 1e-5f);
    s_sc[c] = sc;
    s_sh[c] = b[c] - mean * sc;
  }
  __syncthreads();
  const int i = blockIdx.x * blockDim.x + threadIdx.x;
  if (i >= n4) return;
  const int c0 = (i & (HID / 4 - 1)) * 4;
  const float4 v = ((const float4*)preBN)[i];
  float o[4];
  o[0] = fmaxf(fmaf(v.x, s_sc[c0 + 0], s_sh[c0 + 0]), 0.f);
  o[1] = fmaxf(fmaf(v.y, s_sc[c0 + 1], s_sh[c0 + 1]), 0.f);
  o[2] = fmaxf(fmaf(v.z, s_sc[c0 + 2], s_sh[c0 + 2]), 0.f);
  o[3] = fmaxf(fmaf(v.w, s_sc[c0 + 3], s_sh[c0 + 3]), 0.f);
  ushort_t h[4], l[4];
#pragma unroll
  for (int k = 0; k < 4; ++k) split2(o[k], h[k], l[k]);
  ((ushort4*)hh)[i] = make_ushort4(h[0], h[1], h[2], h[3]);
  ((ushort4*)hl)[i] = make_ushort4(l[0], l[1], l[2], l[3]);
  if (hout) ((float4*)hout)[i] = make_float4(o[0], o[1], o[2], o[3]);
}

// ---------------- softmax over graphs ----------------
__device__ __forceinline__ unsigned fflip(float f) {
  unsigned u = __float_as_uint(f);
  return (u & 0x80000000u) ? ~u : (u | 0x80000000u);
}
__device__ __forceinline__ float funflip(unsigned u) {
  return __uint_as_float((u & 0x80000000u) ? (u ^ 0x80000000u) : ~u);
}

__global__ void seg_max_kernel(const float* __restrict__ s, const int* __restrict__ batch,
                               unsigned* __restrict__ gmax, int M) {
  __shared__ unsigned lmax[NGRAPH];
  if (threadIdx.x < NGRAPH) lmax[threadIdx.x] = 0u;
  __syncthreads();
  for (int i = blockIdx.x * blockDim.x + threadIdx.x; i < M; i += gridDim.x * blockDim.x)
    atomicMax(&lmax[batch[i]], fflip(s[i]));
  __syncthreads();
  if (threadIdx.x < NGRAPH && lmax[threadIdx.x] != 0u) atomicMax(&gmax[threadIdx.x], lmax[threadIdx.x]);
}

__global__ void seg_expsum_kernel(const float* __restrict__ s, const int* __restrict__ batch,
                                  const unsigned* __restrict__ gmax, float* __restrict__ e,
                                  float* __restrict__ denom, int M) {
  __shared__ float ld[NGRAPH];
  if (threadIdx.x < NGRAPH) ld[threadIdx.x] = 0.f;
  __syncthreads();
  for (int i = blockIdx.x * blockDim.x + threadIdx.x; i < M; i += gridDim.x * blockDim.x) {
    const int b = batch[i];
    const float v = expf(s[i] - funflip(gmax[b]));
    e[i] = v;
    atomicAdd(&ld[b], v);
  }
  __syncthreads();
  if (threadIdx.x < NGRAPH && ld[threadIdx.x] != 0.f) atomicAdd(&denom[threadIdx.x], ld[threadIdx.x]);
}

#define PNB 16
__global__ __launch_bounds__(256) void pool_kernel(
    const float* __restrict__ h, const float* __restrict__ e, const float* __restrict__ denom,
    const int* __restrict__ batch, float* __restrict__ pooled, int M) {
  const int wid = (blockIdx.x * blockDim.x + threadIdx.x) >> 6;
  const int lane = threadIdx.x & 63;
  const int n0 = wid * PNB;
  if (n0 >= M) return;
  const int n1 = min(n0 + PNB, M);
  float4 acc = make_float4(0.f, 0.f, 0.f, 0.f);
  int cur = batch[n0];
  for (int n = n0; n < n1; ++n) {
    const int b = batch[n];
    if (b != cur) {
      float* o = pooled + (size_t)cur * HID + lane * 4;
      atomicAdd(o + 0, acc.x); atomicAdd(o + 1, acc.y);
      atomicAdd(o + 2, acc.z); atomicAdd(o + 3, acc.w);
      acc = make_float4(0.f, 0.f, 0.f, 0.f);
      cur = b;
    }
    const float w = e[n] / denom[b];
    const float4 v = ((const float4*)(h + (size_t)n * HID))[lane];
    acc.x = fmaf(v.x, w, acc.x); acc.y = fmaf(v.y, w, acc.y);
    acc.z = fmaf(v.z, w, acc.z); acc.w = fmaf(v.w, w, acc.w);
  }
  float* o = pooled + (size_t)cur * HID + lane * 4;
  atomicAdd(o + 0, acc.x); atomicAdd(o + 1, acc.y);
  atomicAdd(o + 2, acc.z); atomicAdd(o + 3, acc.w);
}

__global__ __launch_bounds__(128) void classifier_kernel(
    const float* __restrict__ pooled, const float* __restrict__ Wc1, const float* __restrict__ bc1,
    const float* __restrict__ Wc2, const float* __restrict__ bc2, float* __restrict__ out) {
  __shared__ float red[128];
  const int g = blockIdx.x;
  const int j = threadIdx.x;
  float acc = bc1[j];
  const float* p = pooled + (size_t)g * HID;
  for (int c = 0; c < HID; ++c) acc = fmaf(p[c], Wc1[c * 128 + j], acc);
  red[j] = fmaxf(acc, 0.f) * Wc2[j];
  __syncthreads();
  for (int off = 64; off > 0; off >>= 1) {
    if (j < off) red[j] += red[j + off];
    __syncthreads();
  }
  if (j == 0) out[g] = red[0] + bc2[0];
}

extern "C" void kernel_launch(void* const* d_in, const int* in_sizes, int n_in,
                              void* d_out, int out_size, void* d_ws, size_t ws_size,
                              hipStream_t stream) {
  const float* x = (const float*)d_in[0];
  const int* edge = (const int*)d_in[1];
  const int* batch = (const int*)d_in[2];
  const int M = in_sizes[2];
  const int nE = in_sizes[1] / 2;
  const int IN_DIM = in_sizes[0] / M;  // 771
  const int* src = edge;
  const int* dst = edge + nE;

  const int Mpad = ((M + 255) / 256) * 256;  // 256-tile GEMM padding
  const int KP0 = ((IN_DIM + 31) / 32) * 32;  // 800
  const int mblocks = (M + 127) / 128;        // att kernel tiles
  const int mb256 = (M + 255) / 256;          // gemm512 tiles

  float* ws = (float*)d_ws;
  float* gbuf = ws;                                    // [M][512]
  float* pbuf = gbuf + (size_t)M * 512;                // [M][256]
  float* h32 = pbuf + (size_t)M * HID;                 // [M][256]
  float* ssc = h32 + (size_t)M * HID;                  // M
  float* ew = ssc + M;                                 // M
  float* bsumA = ew + M;                               // 3 layers x (256 sum + 256 sq)
  unsigned* gmax = (unsigned*)(bsumA + 6 * HID);       // 64
  float* denom = (float*)(gmax + NGRAPH);              // 64
  float* pooled = denom + NGRAPH;                      // 64*256
  int* degi = (int*)(pooled + (size_t)NGRAPH * HID);   // M
  int* filla = degi + M;                               // M
  int* rowptr = filla + M;                             // M+1
  int* csr_src = rowptr + M + 1;                       // nE

  ushort_t* wp = (ushort_t*)(((uintptr_t)(csr_src + nE) + 15) & ~(uintptr_t)15);
  ushort_t* w0h = wp;                 ushort_t* w0l = w0h + (size_t)512 * KP0;
  ushort_t* w1h = w0l + (size_t)512 * KP0;  ushort_t* w1l = w1h + (size_t)512 * HID;
  ushort_t* w2h = w1l + (size_t)512 * HID;  ushort_t* w2l = w2h + (size_t)512 * HID;
  ushort_t* wah = w2l + (size_t)512 * HID;  ushort_t* wal = wah + (size_t)128 * HID;
  ushort_t* cvh = (ushort_t*)(((uintptr_t)(wal + (size_t)128 * HID) + 15) & ~(uintptr_t)15);
  ushort_t* cvl = cvh + (size_t)Mpad * KP0;

  // ---- CSR build ----
  hipMemsetAsync(degi, 0, (size_t)(2 * M) * sizeof(int), stream);
  deg_count_kernel<<<(nE + 255) / 256, 256, 0, stream>>>(dst, degi, nE);
  scan_kernel<<<1, 1024, 0, stream>>>(degi, rowptr, M);
  fill_kernel<<<(nE + 255) / 256, 256, 0, stream>>>(src, dst, filla, rowptr, csr_src, nE);
  // one memset for all small accumulators: bsumA(1536) + gmax(64) + denom(64) + pooled(16384)
  hipMemsetAsync(bsumA, 0, (size_t)(6 * HID + 2 * NGRAPH + NGRAPH * HID) * 4, stream);

  // ---- weight transpose + split (fused Wl||Wr per layer) ----
  {
    const int nt0 = 512 * KP0;
    convert_wt_kernel<<<(nt0 + 255) / 256, 256, 0, stream>>>(
        (const float*)d_in[3], (const float*)d_in[5], w0h, w0l, IN_DIM, KP0, 512, HID);
    const int nt1 = 512 * HID;
    convert_wt_kernel<<<(nt1 + 255) / 256, 256, 0, stream>>>(
        (const float*)d_in[8], (const float*)d_in[10], w1h, w1l, HID, HID, 512, HID);
    convert_wt_kernel<<<(nt1 + 255) / 256, 256, 0, stream>>>(
        (const float*)d_in[13], (const float*)d_in[15], w2h, w2l, HID, HID, 512, HID);
    convert_wt_kernel<<<(128 * HID + 255) / 256, 256, 0, stream>>>(
        (const float*)d_in[18], nullptr, wah, wal, HID, HID, 128, 128);
  }

  // layer-0 input split (+ zero the 256-pad tail rows for the KP0-stride layout)
  {
    const int nt = M * (KP0 / 4);
    convert_x_kernel<<<(nt + 255) / 256, 256, 0, stream>>>(x, M, cvh, cvl, IN_DIM, KP0);
    if (Mpad > M) {
      hipMemsetAsync(cvh + (size_t)M * KP0, 0, (size_t)(Mpad - M) * KP0 * 2, stream);
      hipMemsetAsync(cvl + (size_t)M * KP0, 0, (size_t)(Mpad - M) * KP0 * 2, stream);
    }
  }

  const int n4 = (int)((size_t)M * HID / 4);
  const ushort_t* WH[3] = {w0h, w1h, w2h};
  const ushort_t* WL[3] = {w0l, w1l, w2l};
  for (int l = 0; l < 3; ++l) {
    const int KP = (l == 0) ? KP0 : HID;
    const float* bl = (const float*)d_in[3 + l * 5 + 1];
    const float* gg = (const float*)d_in[3 + l * 5 + 3];
    const float* bb = (const float*)d_in[3 + l * 5 + 4];
    float* bsum = bsumA + l * 512;
    float* bsumsq = bsum + HID;

    dim3 g(2, mb256);
    mfma_gemm512_kernel<<<g, 512, 0, stream>>>(cvh, cvl, WH[l], WL[l], gbuf, M, KP);
    gather_combine_kernel<<<(M + GNB - 1) / GNB, 256, 0, stream>>>(
        gbuf, rowptr, csr_src, bl, pbuf, bsum, bsumsq, M);
    // overwrite cvh/cvl with next layer's split ([Mpad][256] fits in [Mpad][800] region)
    bn_apply_relu_convert_kernel<<<(n4 + 255) / 256, 256, 0, stream>>>(
        pbuf, bsum, bsumsq, gg, bb, cvh, cvl, (l == 2) ? h32 : nullptr, M, n4);
    if (l == 0 && Mpad > M) {
      // zero the pad tail once for the HID-stride layout (layers 1,2 + att)
      hipMemsetAsync(cvh + (size_t)M * HID, 0, (size_t)(Mpad - M) * HID * 2, stream);
      hipMemsetAsync(cvl + (size_t)M * HID, 0, (size_t)(Mpad - M) * HID * 2, stream);
    }
  }

  // attention scores (GEMM + fused tanh-dot epilogue)
  {
    dim3 g(1, mblocks);
    mfma_att_kernel<<<g, 256, 0, stream>>>(
        cvh, cvl, wah, wal, (const float*)d_in[19], (const float*)d_in[20],
        (const float*)d_in[21], ssc, M, HID);
  }
  seg_max_kernel<<<512, 256, 0, stream>>>(ssc, batch, gmax, M);
  seg_expsum_kernel<<<512, 256, 0, stream>>>(ssc, batch, gmax, ew, denom, M);
  {
    const int nwaves = (M + PNB - 1) / PNB;
    pool_kernel<<<(nwaves * 64 + 255) / 256, 256, 0, stream>>>(h32, ew, denom, batch, pooled, M);
  }
  classifier_kernel<<<NGRAPH, 128, 0, stream>>>(
      pooled, (const float*)d_in[22], (const float*)d_in[23],
      (const float*)d_in[24], (const float*)d_in[25], (float*)d_out);
}

// Round 3
// 2041.062 us; speedup vs baseline: 1.0298x; 1.0046x over previous
//
#include <hip/hip_runtime.h>
#include <math.h>
#include <stdint.h>

#define HID 256
#define NGRAPH 64
typedef unsigned short ushort_t;

typedef __attribute__((ext_vector_type(8))) short short8;
typedef __attribute__((ext_vector_type(4))) float f32x4;

// exact fp32 -> bf16 hi/lo split (RNE both)
__device__ __forceinline__ void split2(float v, ushort_t& h, ushort_t& l) {
  unsigned u = __float_as_uint(v);
  unsigned hr = u + 0x7FFFu + ((u >> 16) & 1u);
  h = (ushort_t)(hr >> 16);
  float hf = __uint_as_float(((unsigned)h) << 16);
  float r = v - hf;
  unsigned u2 = __float_as_uint(r);
  unsigned lr = u2 + 0x7FFFu + ((u2 >> 16) & 1u);
  l = (ushort_t)(lr >> 16);
}

#define GLDS(g, l) \
  __builtin_amdgcn_global_load_lds((const __attribute__((address_space(1))) void*)(g), \
                                   (__attribute__((address_space(3))) void*)(l), 16, 0, 0)

// ---------------- MFMA split-bf16 GEMM, fused N=512 ----------------
// A: [Mpad][Kpad] bf16 hi/lo. B: [512][Kpad] bf16 hi/lo (Wl^T rows 0-255, Wr^T 256-511).
// C: [M][512] fp32 = A*B^T (3-term split: hh + hl + lh)
//
// 256x256 tile, 8 waves (2M x 4N), BK=32, 2 LDS buffers, 4-PHASE K-step:
// phase p = { ds_read A-frag pair p (+ B at P0) ; lgkm(0)+barrier ;
//             quarter-owner waves stage tile t+2 into the just-freed quarter ;
//             setprio + 24 MFMA }.
// Quarter ownership: wave w consumes A rows wm+32p..+31 in phase p, so the
// global quarter {32p..32p+31} U {128+32p..+31} of buf c is free after phase
// p's barrier; waves 2p,2p+1 (whose staging rows lie in that quarter) then
// issue their 8 global_load_lds for tile t+2. B is fully consumed at P0.
// beta-gate at K-step start: vmcnt(8) (t+1's loads stay in flight) + barrier
// certifies tile-t data landed wave-globally. vmcnt never drains in-loop.
// LDS bank swizzle: slot s of row r holds global chunk s^((r>>1)&3) (applied
// on the GLOBAL source; global_load_lds dest linear); reads XOR back.
__global__ __launch_bounds__(512, 2) void mfma_gemm512_kernel(
    const ushort_t* __restrict__ Ah, const ushort_t* __restrict__ Al,
    const ushort_t* __restrict__ Bh, const ushort_t* __restrict__ Bl,
    float* __restrict__ C, int Mrows, int Kpad) {
  __shared__ ushort_t lA[2][2][256 * 32];  // [buf][hi/lo][row*32 + slot*8 + e]
  __shared__ ushort_t lB[2][2][256 * 32];
  const int tid = threadIdx.x;

  // XCD-bijective block remap (chunked): the 2 N-tiles sharing an A-tile run
  // consecutively on ONE XCD -> A re-reads are L2 hits.
  const unsigned nwg = gridDim.x * gridDim.y;
  const unsigned flat = blockIdx.y * gridDim.x + blockIdx.x;
  const unsigned qq = nwg >> 3, rr = nwg & 7u;
  const unsigned xcd = flat & 7u, idx = flat >> 3;
  const unsigned swz =
      (xcd < rr ? xcd * (qq + 1u) : rr * (qq + 1u) + (xcd - rr) * qq) + idx;
  const int m0 = (int)(swz / gridDim.x) * 256;
  const int n0 = (int)(swz % gridDim.x) * 256;

  const int w = tid >> 6, lane = tid & 63;
  const int wq = w >> 1;                             // staging quarter owner
  const int wm = (w >> 2) * 128, wn = (w & 3) * 64;  // wave tile: 128x64
  const int col = lane & 15, quad = lane >> 4;

  f32x4 acc[8][4];
#pragma unroll
  for (int i = 0; i < 8; ++i)
#pragma unroll
    for (int j = 0; j < 4; ++j) acc[i][j] = (f32x4)(0.f);

  const int nkt = Kpad >> 5;

  // staging map (per thread, 8 GLDS): rows r0s and r0s+128, A+B, hi+lo.
  // Global source chunk g = slot ^ ((row>>1)&3); rows r0s/r0s+128 share g.
  const int r0s = tid >> 2;
  const int g_ = (tid & 3) ^ ((r0s >> 1) & 3);

#define STAGEQ(kt_, s_)                                           \
  {                                                               \
    const size_t kb = (size_t)(kt_) + g_ * 8;                     \
    const size_t gA0 = (size_t)(m0 + r0s) * Kpad + kb;            \
    const size_t gA1 = (size_t)(m0 + r0s + 128) * Kpad + kb;      \
    const size_t gB0 = (size_t)(n0 + r0s) * Kpad + kb;            \
    const size_t gB1 = (size_t)(n0 + r0s + 128) * Kpad + kb;      \
    GLDS(Ah + gA0, &lA[s_][0][tid * 8]);                          \
    GLDS(Ah + gA1, &lA[s_][0][(tid + 512) * 8]);                  \
    GLDS(Al + gA0, &lA[s_][1][tid * 8]);                          \
    GLDS(Al + gA1, &lA[s_][1][(tid + 512) * 8]);                  \
    GLDS(Bh + gB0, &lB[s_][0][tid * 8]);                          \
    GLDS(Bh + gB1, &lB[s_][0][(tid + 512) * 8]);                  \
    GLDS(Bl + gB0, &lB[s_][1][tid * 8]);                          \
    GLDS(Bl + gB1, &lB[s_][1][(tid + 512) * 8]);                  \
  }

// one phase: read A-frag pair p, barrier, conditional stage, 24 MFMAs
#define PHASE(p_)                                                        \
  {                                                                      \
    short8 ah[2], al[2];                                                 \
    _Pragma("unroll") for (int ii = 0; ii < 2; ++ii) {                   \
      const int ar = wm + (2 * (p_) + ii) * 16 + col;                    \
      const int s = (quad ^ ((ar >> 1) & 3)) * 8;                        \
      ah[ii] = *(const short8*)&lA[c][0][ar * 32 + s];                   \
      al[ii] = *(const short8*)&lA[c][1][ar * 32 + s];                   \
    }                                                                    \
    asm volatile("s_waitcnt lgkmcnt(0)\ns_barrier" ::: "memory");        \
    if (st && wq == (p_)) STAGEQ(((t + 2) << 5), c);                     \
    __builtin_amdgcn_s_setprio(1);                                       \
    _Pragma("unroll") for (int ii = 0; ii < 2; ++ii) {                   \
      const int i = 2 * (p_) + ii;                                       \
      _Pragma("unroll") for (int j = 0; j < 4; ++j) {                    \
        acc[i][j] = __builtin_amdgcn_mfma_f32_16x16x32_bf16(ah[ii], Bh_[j], acc[i][j], 0, 0, 0); \
        acc[i][j] = __builtin_amdgcn_mfma_f32_16x16x32_bf16(ah[ii], Bl_[j], acc[i][j], 0, 0, 0); \
        acc[i][j] = __builtin_amdgcn_mfma_f32_16x16x32_bf16(al[ii], Bh_[j], acc[i][j], 0, 0, 0); \
      }                                                                  \
    }                                                                    \
    __builtin_amdgcn_s_setprio(0);                                       \
  }

  // prologue: stage tiles 0 and 1 (every thread its own 8 per tile)
  STAGEQ(0, 0);
  if (nkt > 1) STAGEQ(32, 1);

  for (int t = 0; t < nkt; ++t) {
    const int c = t & 1;
    const bool st = (t + 2 < nkt);
    // beta-gate: tile t landed (wave-global); t+1's 8 loads stay in flight
    if (t + 1 < nkt)
      asm volatile("s_waitcnt vmcnt(8)\ns_barrier" ::: "memory");
    else
      asm volatile("s_waitcnt vmcnt(0)\ns_barrier" ::: "memory");

    // B fragments for all 4 n-tiles (read once per K-step, phase-0 read set)
    short8 Bh_[4], Bl_[4];
#pragma unroll
    for (int j = 0; j < 4; ++j) {
      const int br = wn + j * 16 + col;
      const int s = (quad ^ ((br >> 1) & 3)) * 8;
      Bh_[j] = *(const short8*)&lB[c][0][br * 32 + s];
      Bl_[j] = *(const short8*)&lB[c][1][br * 32 + s];
    }
    PHASE(0)
    PHASE(1)
    PHASE(2)
    PHASE(3)
  }
#undef STAGEQ
#undef PHASE

#pragma unroll
  for (int i = 0; i < 8; ++i) {
    const int r0 = m0 + wm + i * 16 + quad * 4;
#pragma unroll
    for (int j = 0; j < 4; ++j) {
      const int cc = n0 + wn + j * 16 + col;
#pragma unroll
      for (int r = 0; r < 4; ++r)
        if (r0 + r < Mrows) C[(size_t)(r0 + r) * 512 + cc] = acc[i][j][r];
    }
  }
}

// ---------------- attention GEMM (N=128) with fused tanh-dot scorer ----------------
// computes t = h@Wa1 per 128x128 tile, then s[m] = sum_c tanh(t[m][c]+ba1[c])*Wa2[c] + ba2
__global__ __launch_bounds__(256) void mfma_att_kernel(
    const ushort_t* __restrict__ Ah, const ushort_t* __restrict__ Al,
    const ushort_t* __restrict__ Bh, const ushort_t* __restrict__ Bl,
    const float* __restrict__ ba1, const float* __restrict__ Wa2,
    const float* __restrict__ ba2, float* __restrict__ S, int Mrows, int Kpad) {
  __shared__ ushort_t lAh[128 * 32];
  __shared__ ushort_t lAl[128 * 32];
  __shared__ ushort_t lBh[128 * 32];
  __shared__ ushort_t lBl[128 * 32];
  __shared__ float sat[128][2];
  const int tid = threadIdx.x;
  const int m0 = blockIdx.y * 128;
  const int w = tid >> 6, lane = tid & 63;
  const int wm = (w >> 1) * 64, wn = (w & 1) * 64;
  const int col = lane & 15, quad = lane >> 4;

  f32x4 acc[4][4];
#pragma unroll
  for (int i = 0; i < 4; ++i)
#pragma unroll
    for (int j = 0; j < 4; ++j) acc[i][j] = (f32x4)(0.f);

  for (int kt = 0; kt < Kpad; kt += 32) {
#pragma unroll
    for (int j = 0; j < 2; ++j) {
      const int ch = tid + j * 256;
      const int r = ch >> 2, c = ch & 3;
      const size_t goA = (size_t)(m0 + r) * Kpad + kt + c * 8;
      const size_t goB = (size_t)r * Kpad + kt + c * 8;
      GLDS(Ah + goA, &lAh[ch * 8]);
      GLDS(Al + goA, &lAl[ch * 8]);
      GLDS(Bh + goB, &lBh[ch * 8]);
      GLDS(Bl + goB, &lBl[ch * 8]);
    }
    __syncthreads();
    short8 ah[4], al[4], bh[4], bl[4];
#pragma unroll
    for (int i = 0; i < 4; ++i) {
      const int ar = wm + i * 16 + col;
      ah[i] = *(const short8*)&lAh[ar * 32 + quad * 8];
      al[i] = *(const short8*)&lAl[ar * 32 + quad * 8];
      const int br = wn + i * 16 + col;
      bh[i] = *(const short8*)&lBh[br * 32 + quad * 8];
      bl[i] = *(const short8*)&lBl[br * 32 + quad * 8];
    }
    __syncthreads();
#pragma unroll
    for (int i = 0; i < 4; ++i)
#pragma unroll
      for (int j = 0; j < 4; ++j) {
        acc[i][j] = __builtin_amdgcn_mfma_f32_16x16x32_bf16(ah[i], bh[j], acc[i][j], 0, 0, 0);
        acc[i][j] = __builtin_amdgcn_mfma_f32_16x16x32_bf16(ah[i], bl[j], acc[i][j], 0, 0, 0);
        acc[i][j] = __builtin_amdgcn_mfma_f32_16x16x32_bf16(al[i], bh[j], acc[i][j], 0, 0, 0);
      }
  }
  // epilogue: per-row tanh-dot
  float part[4][4];
#pragma unroll
  for (int i = 0; i < 4; ++i)
#pragma unroll
    for (int r = 0; r < 4; ++r) part[i][r] = 0.f;
#pragma unroll
  for (int j = 0; j < 4; ++j) {
    const int cc = wn + j * 16 + col;
    const float a1 = ba1[cc];
    const float w2 = Wa2[cc];
#pragma unroll
    for (int i = 0; i < 4; ++i)
#pragma unroll
      for (int r = 0; r < 4; ++r)
        part[i][r] += tanhf(acc[i][j][r] + a1) * w2;
  }
#pragma unroll
  for (int mask = 1; mask < 16; mask <<= 1)
#pragma unroll
    for (int i = 0; i < 4; ++i)
#pragma unroll
      for (int r = 0; r < 4; ++r) part[i][r] += __shfl_xor(part[i][r], mask, 64);
  if (col == 0) {
#pragma unroll
    for (int i = 0; i < 4; ++i)
#pragma unroll
      for (int r = 0; r < 4; ++r) sat[wm + i * 16 + quad * 4 + r][wn >> 6] = part[i][r];
  }
  __syncthreads();
  if (tid < 128) {
    const int gm = m0 + tid;
    if (gm < Mrows) S[gm] = sat[tid][0] + sat[tid][1] + ba2[0];
  }
}

// ---------------- conversions ----------------
__global__ __launch_bounds__(256) void convert_x_kernel(
    const float* __restrict__ x, int nrows,
    ushort_t* __restrict__ xh, ushort_t* __restrict__ xl, int K, int Kpad) {
  const int perRow = Kpad / 4;
  const int t = blockIdx.x * blockDim.x + threadIdx.x;
  if (t >= nrows * perRow) return;
  const int r = t / perRow, k0 = (t % perRow) * 4;
  const float* xr = x + (size_t)r * K;
  ushort_t h[4], l[4];
#pragma unroll
  for (int i = 0; i < 4; ++i) {
    const float v = (k0 + i < K) ? xr[k0 + i] : 0.f;
    split2(v, h[i], l[i]);
  }
  const size_t o = (size_t)r * Kpad + k0;
  *(ushort4*)(xh + o) = make_ushort4(h[0], h[1], h[2], h[3]);
  *(ushort4*)(xl + o) = make_ushort4(l[0], l[1], l[2], l[3]);
}

// fused transpose+split: rows n<256 from W1[k][n], n>=256 from W2[k][n-256]
__global__ void convert_wt_kernel(const float* __restrict__ W1, const float* __restrict__ W2,
                                  ushort_t* __restrict__ wth, ushort_t* __restrict__ wtl,
                                  int K, int Kpad, int ntot, int ld) {
  const int t = blockIdx.x * blockDim.x + threadIdx.x;
  if (t >= ntot * Kpad) return;
  const int n = t / Kpad, k = t % Kpad;
  float v = 0.f;
  if (k < K) v = (n < 256) ? W1[(size_t)k * ld + n] : W2[(size_t)k * ld + (n - 256)];
  ushort_t h, l;
  split2(v, h, l);
  wth[t] = h;
  wtl[t] = l;
}

// ---------------- CSR build ----------------
__global__ void deg_count_kernel(const int* __restrict__ dst, int* __restrict__ degi, int nE) {
  int e = blockIdx.x * blockDim.x + threadIdx.x;
  if (e < nE) atomicAdd(&degi[dst[e]], 1);
}

__global__ __launch_bounds__(1024) void scan_kernel(const int* __restrict__ degi,
                                                    int* __restrict__ rowptr, int M) {
  __shared__ int part[1024];
  const int t = threadIdx.x;
  const int chunk = (M + 1023) / 1024;
  const int b0 = min(t * chunk, M);
  const int b1 = min(b0 + chunk, M);
  int s = 0;
  for (int i = b0; i < b1; ++i) s += degi[i];
  part[t] = s;
  __syncthreads();
  for (int off = 1; off < 1024; off <<= 1) {
    int v = (t >= off) ? part[t - off] : 0;
    __syncthreads();
    part[t] += v;
    __syncthreads();
  }
  int ex = (t == 0) ? 0 : part[t - 1];
  for (int i = b0; i < b1; ++i) {
    rowptr[i] = ex;
    ex += degi[i];
  }
  if (t == 1023) rowptr[M] = part[1023];
}

__global__ void fill_kernel(const int* __restrict__ src, const int* __restrict__ dst,
                            int* __restrict__ fill, const int* __restrict__ rowptr,
                            int* __restrict__ csr_src, int nE) {
  int e = blockIdx.x * blockDim.x + threadIdx.x;
  if (e >= nE) return;
  const int d = dst[e];
  const int pos = rowptr[d] + atomicAdd(&fill[d], 1);
  csr_src[pos] = src[e];
}

// ---------------- fused gather-mean + bias + hr + BN stats ----------------
// gbuf: [M][512] (cols 0-255 = hl, 256-511 = hr)
#define GNB 64
__global__ __launch_bounds__(256) void gather_combine_kernel(
    const float* __restrict__ gbuf,
    const int* __restrict__ rowptr, const int* __restrict__ csr_src,
    const float* __restrict__ bl, float* preBN,
    float* __restrict__ bsum, float* __restrict__ bsumsq, int M) {
  __shared__ float lsum[4][HID];
  __shared__ float lsq[4][HID];
  const int w = threadIdx.x >> 6;
  const int lane = threadIdx.x & 63;
  const float4 blv = ((const float4*)bl)[lane];
  float4 s = make_float4(0.f, 0.f, 0.f, 0.f);
  float4 q = make_float4(0.f, 0.f, 0.f, 0.f);
  const int base = blockIdx.x * GNB;
  for (int it = 0; it < GNB / 4; ++it) {
    const int n = base + it * 4 + w;
    if (n < M) {
      const int e0 = rowptr[n], e1 = rowptr[n + 1];
      float4 acc = make_float4(0.f, 0.f, 0.f, 0.f);
      float4 acc2 = make_float4(0.f, 0.f, 0.f, 0.f);
      int e = e0;
      // 2-edge unroll: two independent gather rows in flight (latency-bound)
      for (; e + 2 <= e1; e += 2) {
        const int sn0 = csr_src[e];
        const int sn1 = csr_src[e + 1];
        const float4 v0 = ((const float4*)(gbuf + (size_t)sn0 * 512))[lane];
        const float4 v1 = ((const float4*)(gbuf + (size_t)sn1 * 512))[lane];
        acc.x += v0.x; acc.y += v0.y; acc.z += v0.z; acc.w += v0.w;
        acc2.x += v1.x; acc2.y += v1.y; acc2.z += v1.z; acc2.w += v1.w;
      }
      if (e < e1) {
        const int sn = csr_src[e];
        const float4 v = ((const float4*)(gbuf + (size_t)sn * 512))[lane];
        acc.x += v.x; acc.y += v.y; acc.z += v.z; acc.w += v.w;
      }
      acc.x += acc2.x; acc.y += acc2.y; acc.z += acc2.z; acc.w += acc2.w;
      const float rd = 1.0f / fmaxf((float)(e1 - e0), 1.0f);
      const float4 hv = ((const float4*)(gbuf + (size_t)n * 512 + 256))[lane];
      float4 o;
      o.x = fmaf(acc.x, rd, blv.x + hv.x);
      o.y = fmaf(acc.y, rd, blv.y + hv.y);
      o.z = fmaf(acc.z, rd, blv.z + hv.z);
      o.w = fmaf(acc.w, rd, blv.w + hv.w);
      ((float4*)(preBN + (size_t)n * HID))[lane] = o;
      s.x += o.x; s.y += o.y; s.z += o.z; s.w += o.w;
      q.x = fmaf(o.x, o.x, q.x); q.y = fmaf(o.y, o.y, q.y);
      q.z = fmaf(o.z, o.z, q.z); q.w = fmaf(o.w, o.w, q.w);
    }
  }
  *(float4*)&lsum[w][lane * 4] = s;
  *(float4*)&lsq[w][lane * 4] = q;
  __syncthreads();
  const int c = threadIdx.x;
  const float ts = lsum[0][c] + lsum[1][c] + lsum[2][c] + lsum[3][c];
  const float tq = lsq[0][c] + lsq[1][c] + lsq[2][c] + lsq[3][c];
  atomicAdd(&bsum[c], ts);
  atomicAdd(&bsumsq[c], tq);
}

// BN(scale/shift recomputed per block) + ReLU -> bf16 split (+ optional fp32)
__global__ __launch_bounds__(256) void bn_apply_relu_convert_kernel(
    const float* __restrict__ preBN, const float* __restrict__ bsum,
    const float* __restrict__ bsumsq, const float* __restrict__ g, const float* __restrict__ b,
    ushort_t* __restrict__ hh, ushort_t* __restrict__ hl, float* __restrict__ hout,
    int M, int n4) {
  __shared__ float s_sc[HID], s_sh[HID];
  {
    const int c = threadIdx.x;
    const float inv = 1.0f / (float)M;
    const float mean = bsum[c] * inv;
    const float var = bsumsq[c] * inv - mean * mean;
    const float sc = g[c] * rsqrtf(var + 1e-5f);
    s_sc[c] = sc;
    s_sh[c] = b[c] - mean * sc;
  }
  __syncthreads();
  const int i = blockIdx.x * blockDim.x + threadIdx.x;
  if (i >= n4) return;
  const int c0 = (i & (HID / 4 - 1)) * 4;
  const float4 v = ((const float4*)preBN)[i];
  float o[4];
  o[0] = fmaxf(fmaf(v.x, s_sc[c0 + 0], s_sh[c0 + 0]), 0.f);
  o[1] = fmaxf(fmaf(v.y, s_sc[c0 + 1], s_sh[c0 + 1]), 0.f);
  o[2] = fmaxf(fmaf(v.z, s_sc[c0 + 2], s_sh[c0 + 2]), 0.f);
  o[3] = fmaxf(fmaf(v.w, s_sc[c0 + 3], s_sh[c0 + 3]), 0.f);
  ushort_t h[4], l[4];
#pragma unroll
  for (int k = 0; k < 4; ++k) split2(o[k], h[k], l[k]);
  ((ushort4*)hh)[i] = make_ushort4(h[0], h[1], h[2], h[3]);
  ((ushort4*)hl)[i] = make_ushort4(l[0], l[1], l[2], l[3]);
  if (hout) ((float4*)hout)[i] = make_float4(o[0], o[1], o[2], o[3]);
}

// ---------------- softmax over graphs ----------------
__device__ __forceinline__ unsigned fflip(float f) {
  unsigned u = __float_as_uint(f);
  return (u & 0x80000000u) ? ~u : (u | 0x80000000u);
}
__device__ __forceinline__ float funflip(unsigned u) {
  return __uint_as_float((u & 0x80000000u) ? (u ^ 0x80000000u) : ~u);
}

__global__ void seg_max_kernel(const float* __restrict__ s, const int* __restrict__ batch,
                               unsigned* __restrict__ gmax, int M) {
  __shared__ unsigned lmax[NGRAPH];
  if (threadIdx.x < NGRAPH) lmax[threadIdx.x] = 0u;
  __syncthreads();
  for (int i = blockIdx.x * blockDim.x + threadIdx.x; i < M; i += gridDim.x * blockDim.x)
    atomicMax(&lmax[batch[i]], fflip(s[i]));
  __syncthreads();
  if (threadIdx.x < NGRAPH && lmax[threadIdx.x] != 0u) atomicMax(&gmax[threadIdx.x], lmax[threadIdx.x]);
}

__global__ void seg_expsum_kernel(const float* __restrict__ s, const int* __restrict__ batch,
                                  const unsigned* __restrict__ gmax, float* __restrict__ e,
                                  float* __restrict__ denom, int M) {
  __shared__ float ld[NGRAPH];
  if (threadIdx.x < NGRAPH) ld[threadIdx.x] = 0.f;
  __syncthreads();
  for (int i = blockIdx.x * blockDim.x + threadIdx.x; i < M; i += gridDim.x * blockDim.x) {
    const int b = batch[i];
    const float v = expf(s[i] - funflip(gmax[b]));
    e[i] = v;
    atomicAdd(&ld[b], v);
  }
  __syncthreads();
  if (threadIdx.x < NGRAPH && ld[threadIdx.x] != 0.f) atomicAdd(&denom[threadIdx.x], ld[threadIdx.x]);
}

#define PNB 16
__global__ __launch_bounds__(256) void pool_kernel(
    const float* __restrict__ h, const float* __restrict__ e, const float* __restrict__ denom,
    const int* __restrict__ batch, float* __restrict__ pooled, int M) {
  const int wid = (blockIdx.x * blockDim.x + threadIdx.x) >> 6;
  const int lane = threadIdx.x & 63;
  const int n0 = wid * PNB;
  if (n0 >= M) return;
  const int n1 = min(n0 + PNB, M);
  float4 acc = make_float4(0.f, 0.f, 0.f, 0.f);
  int cur = batch[n0];
  for (int n = n0; n < n1; ++n) {
    const int b = batch[n];
    if (b != cur) {
      float* o = pooled + (size_t)cur * HID + lane * 4;
      atomicAdd(o + 0, acc.x); atomicAdd(o + 1, acc.y);
      atomicAdd(o + 2, acc.z); atomicAdd(o + 3, acc.w);
      acc = make_float4(0.f, 0.f, 0.f, 0.f);
      cur = b;
    }
    const float w = e[n] / denom[b];
    const float4 v = ((const float4*)(h + (size_t)n * HID))[lane];
    acc.x = fmaf(v.x, w, acc.x); acc.y = fmaf(v.y, w, acc.y);
    acc.z = fmaf(v.z, w, acc.z); acc.w = fmaf(v.w, w, acc.w);
  }
  float* o = pooled + (size_t)cur * HID + lane * 4;
  atomicAdd(o + 0, acc.x); atomicAdd(o + 1, acc.y);
  atomicAdd(o + 2, acc.z); atomicAdd(o + 3, acc.w);
}

__global__ __launch_bounds__(128) void classifier_kernel(
    const float* __restrict__ pooled, const float* __restrict__ Wc1, const float* __restrict__ bc1,
    const float* __restrict__ Wc2, const float* __restrict__ bc2, float* __restrict__ out) {
  __shared__ float red[128];
  const int g = blockIdx.x;
  const int j = threadIdx.x;
  float acc = bc1[j];
  const float* p = pooled + (size_t)g * HID;
  for (int c = 0; c < HID; ++c) acc = fmaf(p[c], Wc1[c * 128 + j], acc);
  red[j] = fmaxf(acc, 0.f) * Wc2[j];
  __syncthreads();
  for (int off = 64; off > 0; off >>= 1) {
    if (j < off) red[j] += red[j + off];
    __syncthreads();
  }
  if (j == 0) out[g] = red[0] + bc2[0];
}

extern "C" void kernel_launch(void* const* d_in, const int* in_sizes, int n_in,
                              void* d_out, int out_size, void* d_ws, size_t ws_size,
                              hipStream_t stream) {
  const float* x = (const float*)d_in[0];
  const int* edge = (const int*)d_in[1];
  const int* batch = (const int*)d_in[2];
  const int M = in_sizes[2];
  const int nE = in_sizes[1] / 2;
  const int IN_DIM = in_sizes[0] / M;  // 771
  const int* src = edge;
  const int* dst = edge + nE;

  const int Mpad = ((M + 255) / 256) * 256;  // 256-tile GEMM padding
  const int KP0 = ((IN_DIM + 31) / 32) * 32;  // 800
  const int mblocks = (M + 127) / 128;        // att kernel tiles
  const int mb256 = (M + 255) / 256;          // gemm512 tiles

  float* ws = (float*)d_ws;
  float* gbuf = ws;                                    // [M][512]
  float* pbuf = gbuf + (size_t)M * 512;                // [M][256]
  float* h32 = pbuf + (size_t)M * HID;                 // [M][256]
  float* ssc = h32 + (size_t)M * HID;                  // M
  float* ew = ssc + M;                                 // M
  float* bsumA = ew + M;                               // 3 layers x (256 sum + 256 sq)
  unsigned* gmax = (unsigned*)(bsumA + 6 * HID);       // 64
  float* denom = (float*)(gmax + NGRAPH);              // 64
  float* pooled = denom + NGRAPH;                      // 64*256
  int* degi = (int*)(pooled + (size_t)NGRAPH * HID);   // M
  int* filla = degi + M;                               // M
  int* rowptr = filla + M;                             // M+1
  int* csr_src = rowptr + M + 1;                       // nE

  ushort_t* wp = (ushort_t*)(((uintptr_t)(csr_src + nE) + 15) & ~(uintptr_t)15);
  ushort_t* w0h = wp;                 ushort_t* w0l = w0h + (size_t)512 * KP0;
  ushort_t* w1h = w0l + (size_t)512 * KP0;  ushort_t* w1l = w1h + (size_t)512 * HID;
  ushort_t* w2h = w1l + (size_t)512 * HID;  ushort_t* w2l = w2h + (size_t)512 * HID;
  ushort_t* wah = w2l + (size_t)512 * HID;  ushort_t* wal = wah + (size_t)128 * HID;
  ushort_t* cvh = (ushort_t*)(((uintptr_t)(wal + (size_t)128 * HID) + 15) & ~(uintptr_t)15);
  ushort_t* cvl = cvh + (size_t)Mpad * KP0;

  // ---- CSR build ----
  hipMemsetAsync(degi, 0, (size_t)(2 * M) * sizeof(int), stream);
  deg_count_kernel<<<(nE + 255) / 256, 256, 0, stream>>>(dst, degi, nE);
  scan_kernel<<<1, 1024, 0, stream>>>(degi, rowptr, M);
  fill_kernel<<<(nE + 255) / 256, 256, 0, stream>>>(src, dst, filla, rowptr, csr_src, nE);
  // one memset for all small accumulators: bsumA(1536) + gmax(64) + denom(64) + pooled(16384)
  hipMemsetAsync(bsumA, 0, (size_t)(6 * HID + 2 * NGRAPH + NGRAPH * HID) * 4, stream);

  // ---- weight transpose + split (fused Wl||Wr per layer) ----
  {
    const int nt0 = 512 * KP0;
    convert_wt_kernel<<<(nt0 + 255) / 256, 256, 0, stream>>>(
        (const float*)d_in[3], (const float*)d_in[5], w0h, w0l, IN_DIM, KP0, 512, HID);
    const int nt1 = 512 * HID;
    convert_wt_kernel<<<(nt1 + 255) / 256, 256, 0, stream>>>(
        (const float*)d_in[8], (const float*)d_in[10], w1h, w1l, HID, HID, 512, HID);
    convert_wt_kernel<<<(nt1 + 255) / 256, 256, 0, stream>>>(
        (const float*)d_in[13], (const float*)d_in[15], w2h, w2l, HID, HID, 512, HID);
    convert_wt_kernel<<<(128 * HID + 255) / 256, 256, 0, stream>>>(
        (const float*)d_in[18], nullptr, wah, wal, HID, HID, 128, 128);
  }

  // layer-0 input split (+ zero the 256-pad tail rows for the KP0-stride layout)
  {
    const int nt = M * (KP0 / 4);
    convert_x_kernel<<<(nt + 255) / 256, 256, 0, stream>>>(x, M, cvh, cvl, IN_DIM, KP0);
    if (Mpad > M) {
      hipMemsetAsync(cvh + (size_t)M * KP0, 0, (size_t)(Mpad - M) * KP0 * 2, stream);
      hipMemsetAsync(cvl + (size_t)M * KP0, 0, (size_t)(Mpad - M) * KP0 * 2, stream);
    }
  }

  const int n4 = (int)((size_t)M * HID / 4);
  const ushort_t* WH[3] = {w0h, w1h, w2h};
  const ushort_t* WL[3] = {w0l, w1l, w2l};
  for (int l = 0; l < 3; ++l) {
    const int KP = (l == 0) ? KP0 : HID;
    const float* bl = (const float*)d_in[3 + l * 5 + 1];
    const float* gg = (const float*)d_in[3 + l * 5 + 3];
    const float* bb = (const float*)d_in[3 + l * 5 + 4];
    float* bsum = bsumA + l * 512;
    float* bsumsq = bsum + HID;

    dim3 g(2, mb256);
    mfma_gemm512_kernel<<<g, 512, 0, stream>>>(cvh, cvl, WH[l], WL[l], gbuf, M, KP);
    gather_combine_kernel<<<(M + GNB - 1) / GNB, 256, 0, stream>>>(
        gbuf, rowptr, csr_src, bl, pbuf, bsum, bsumsq, M);
    // overwrite cvh/cvl with next layer's split ([Mpad][256] fits in [Mpad][800] region)
    bn_apply_relu_convert_kernel<<<(n4 + 255) / 256, 256, 0, stream>>>(
        pbuf, bsum, bsumsq, gg, bb, cvh, cvl, (l == 2) ? h32 : nullptr, M, n4);
    if (l == 0 && Mpad > M) {
      // zero the pad tail once for the HID-stride layout (layers 1,2 + att)
      hipMemsetAsync(cvh + (size_t)M * HID, 0, (size_t)(Mpad - M) * HID * 2, stream);
      hipMemsetAsync(cvl + (size_t)M * HID, 0, (size_t)(Mpad - M) * HID * 2, stream);
    }
  }

  // attention scores (GEMM + fused tanh-dot epilogue)
  {
    dim3 g(1, mblocks);
    mfma_att_kernel<<<g, 256, 0, stream>>>(
        cvh, cvl, wah, wal, (const float*)d_in[19], (const float*)d_in[20],
        (const float*)d_in[21], ssc, M, HID);
  }
  seg_max_kernel<<<512, 256, 0, stream>>>(ssc, batch, gmax, M);
  seg_expsum_kernel<<<512, 256, 0, stream>>>(ssc, batch, gmax, ew, denom, M);
  {
    const int nwaves = (M + PNB - 1) / PNB;
    pool_kernel<<<(nwaves * 64 + 255) / 256, 256, 0, stream>>>(h32, ew, denom, batch, pooled, M);
  }
  classifier_kernel<<<NGRAPH, 128, 0, stream>>>(
      pooled, (const float*)d_in[22], (const float*)d_in[23],
      (const float*)d_in[24], (const float*)d_in[25], (float*)d_out);
}

// Round 4
// 1991.007 us; speedup vs baseline: 1.0557x; 1.0251x over previous
//
#include <hip/hip_runtime.h>
#include <math.h>
#include <stdint.h>

#define HID 256
#define NGRAPH 64
typedef unsigned short ushort_t;

typedef __attribute__((ext_vector_type(8))) short short8;
typedef __attribute__((ext_vector_type(4))) float f32x4;

// exact fp32 -> bf16 hi/lo split (RNE both)
__device__ __forceinline__ void split2(float v, ushort_t& h, ushort_t& l) {
  unsigned u = __float_as_uint(v);
  unsigned hr = u + 0x7FFFu + ((u >> 16) & 1u);
  h = (ushort_t)(hr >> 16);
  float hf = __uint_as_float(((unsigned)h) << 16);
  float r = v - hf;
  unsigned u2 = __float_as_uint(r);
  unsigned lr = u2 + 0x7FFFu + ((u2 >> 16) & 1u);
  l = (ushort_t)(lr >> 16);
}

#define GLDS(g, l) \
  __builtin_amdgcn_global_load_lds((const __attribute__((address_space(1))) void*)(g), \
                                   (__attribute__((address_space(3))) void*)(l), 16, 0, 0)

// ---------------- MFMA split-bf16 GEMM, fused N=512 ----------------
// A: [Mpad][Kpad] bf16 hi/lo. B: [512][Kpad] bf16 hi/lo (Wl^T rows 0-255, Wr^T 256-511).
// C: [M][512] fp32 = A*B^T (3-term split: hh + hl + lh)
//
// 256x256 tile, 8 waves (2M x 4N), BK=32, 2 LDS buffers, 4-phase K-step in the
// m201 template order: per phase p:
//   { ds_read A-pair p (+ all B at p=0) ;
//     owner(p-1) stages quarter p-1 of tile t+2 (issue BEFORE the barrier) ;
//     s_barrier ; s_waitcnt lgkmcnt(0) ;      // drain AFTER barrier: read
//     setprio(1) ; 24 MFMA ; setprio(0) ;     // latency hides in barrier skew
//     s_barrier }
// Quarter q of buf c (A rows {32q..}+{128+32q..} and same B rows) is fully
// consumed by phase q (every wave's reads drained by its own lgkm0 before it
// reaches phase-q's 2nd barrier), so staging it in phase q+1 pre-barrier is
// race-free. Quarter 3 stages at K-step end. Beta-gate at K-step start
// (vmcnt(8)+barrier) certifies tile t landed wave-globally; each wave issues
// exactly 8 GLDS/K-step so tile t's loads are always the oldest 8 of 16.
// vmcnt never drains to 0 in-loop.
// LDS bank swizzle: slot s of row r holds global chunk s^((r>>1)&3) (applied
// on the GLOBAL source; global_load_lds dest linear); reads XOR back.
__global__ __launch_bounds__(512, 2) void mfma_gemm512_kernel(
    const ushort_t* __restrict__ Ah, const ushort_t* __restrict__ Al,
    const ushort_t* __restrict__ Bh, const ushort_t* __restrict__ Bl,
    float* __restrict__ C, int Mrows, int Kpad) {
  __shared__ ushort_t lA[2][2][256 * 32];  // [buf][hi/lo][row*32 + slot*8 + e]
  __shared__ ushort_t lB[2][2][256 * 32];
  const int tid = threadIdx.x;

  // XCD-bijective block remap (chunked): the 2 N-tiles sharing an A-tile run
  // consecutively on ONE XCD -> A re-reads are L2 hits.
  const unsigned nwg = gridDim.x * gridDim.y;
  const unsigned flat = blockIdx.y * gridDim.x + blockIdx.x;
  const unsigned qq = nwg >> 3, rr = nwg & 7u;
  const unsigned xcd = flat & 7u, idx = flat >> 3;
  const unsigned swz =
      (xcd < rr ? xcd * (qq + 1u) : rr * (qq + 1u) + (xcd - rr) * qq) + idx;
  const int m0 = (int)(swz / gridDim.x) * 256;
  const int n0 = (int)(swz % gridDim.x) * 256;

  const int w = tid >> 6, lane = tid & 63;
  const int wq = w >> 1;                             // staging quarter owner
  const int wm = (w >> 2) * 128, wn = (w & 3) * 64;  // wave tile: 128x64
  const int col = lane & 15, quad = lane >> 4;

  f32x4 acc[8][4];
#pragma unroll
  for (int i = 0; i < 8; ++i)
#pragma unroll
    for (int j = 0; j < 4; ++j) acc[i][j] = (f32x4)(0.f);

  const int nkt = Kpad >> 5;

  // staging map (per thread, 8 GLDS): rows r0s and r0s+128, A+B, hi+lo.
  // Wave-pair {2q,2q+1} (tids 128q..128q+127) covers exactly quarter q.
  // Global source chunk g = slot ^ ((row>>1)&3); rows r0s/r0s+128 share g.
  const int r0s = tid >> 2;
  const int g_ = (tid & 3) ^ ((r0s >> 1) & 3);

#define STAGEQ(kt_, s_)                                           \
  {                                                               \
    const size_t kb = (size_t)(kt_) + g_ * 8;                     \
    const size_t gA0 = (size_t)(m0 + r0s) * Kpad + kb;            \
    const size_t gA1 = (size_t)(m0 + r0s + 128) * Kpad + kb;      \
    const size_t gB0 = (size_t)(n0 + r0s) * Kpad + kb;            \
    const size_t gB1 = (size_t)(n0 + r0s + 128) * Kpad + kb;      \
    GLDS(Ah + gA0, &lA[s_][0][tid * 8]);                          \
    GLDS(Ah + gA1, &lA[s_][0][(tid + 512) * 8]);                  \
    GLDS(Al + gA0, &lA[s_][1][tid * 8]);                          \
    GLDS(Al + gA1, &lA[s_][1][(tid + 512) * 8]);                  \
    GLDS(Bh + gB0, &lB[s_][0][tid * 8]);                          \
    GLDS(Bh + gB1, &lB[s_][0][(tid + 512) * 8]);                  \
    GLDS(Bl + gB0, &lB[s_][1][tid * 8]);                          \
    GLDS(Bl + gB1, &lB[s_][1][(tid + 512) * 8]);                  \
  }

// phase p: {reads ; stage(q=p-1) ; barrier ; lgkm0 ; MFMA i=2p,2p+1 ; barrier}
#define PHASE(p_)                                                        \
  {                                                                      \
    short8 ah[2], al[2];                                                 \
    _Pragma("unroll") for (int ii = 0; ii < 2; ++ii) {                   \
      const int ar = wm + (2 * (p_) + ii) * 16 + col;                    \
      const int s = (quad ^ ((ar >> 1) & 3)) * 8;                        \
      ah[ii] = *(const short8*)&lA[c][0][ar * 32 + s];                   \
      al[ii] = *(const short8*)&lA[c][1][ar * 32 + s];                   \
    }                                                                    \
    if ((p_) > 0 && st && wq == (p_) - 1) STAGEQ(((t + 2) << 5), c);     \
    asm volatile("s_barrier" ::: "memory");                              \
    asm volatile("s_waitcnt lgkmcnt(0)" ::: "memory");                   \
    __builtin_amdgcn_s_setprio(1);                                       \
    _Pragma("unroll") for (int ii = 0; ii < 2; ++ii) {                   \
      const int i = 2 * (p_) + ii;                                       \
      _Pragma("unroll") for (int j = 0; j < 4; ++j) {                    \
        acc[i][j] = __builtin_amdgcn_mfma_f32_16x16x32_bf16(ah[ii], Bh_[j], acc[i][j], 0, 0, 0); \
        acc[i][j] = __builtin_amdgcn_mfma_f32_16x16x32_bf16(ah[ii], Bl_[j], acc[i][j], 0, 0, 0); \
        acc[i][j] = __builtin_amdgcn_mfma_f32_16x16x32_bf16(al[ii], Bh_[j], acc[i][j], 0, 0, 0); \
      }                                                                  \
    }                                                                    \
    __builtin_amdgcn_s_setprio(0);                                       \
    asm volatile("s_barrier" ::: "memory");                              \
  }

  // prologue: stage tiles 0 and 1 fully (every thread its own 8 per tile)
  STAGEQ(0, 0);
  if (nkt > 1) STAGEQ(32, 1);

  for (int t = 0; t < nkt; ++t) {
    const int c = t & 1;
    const bool st = (t + 2 < nkt);
    // beta-gate: tile t landed (wave-global); t+1's 8 loads stay in flight
    if (t + 1 < nkt)
      asm volatile("s_waitcnt vmcnt(8)\ns_barrier" ::: "memory");
    else
      asm volatile("s_waitcnt vmcnt(0)\ns_barrier" ::: "memory");

    // B fragments for all 4 n-tiles (issued with phase 0's read set)
    short8 Bh_[4], Bl_[4];
#pragma unroll
    for (int j = 0; j < 4; ++j) {
      const int br = wn + j * 16 + col;
      const int s = (quad ^ ((br >> 1) & 3)) * 8;
      Bh_[j] = *(const short8*)&lB[c][0][br * 32 + s];
      Bl_[j] = *(const short8*)&lB[c][1][br * 32 + s];
    }
    PHASE(0)
    PHASE(1)
    PHASE(2)
    PHASE(3)
    // quarter 3 of tile t+2: its consumers (phase 3) drained before the last
    // barrier, so issue now; certified landed by beta-gate(t+2)'s vmcnt(8).
    if (st && wq == 3) STAGEQ(((t + 2) << 5), c);
  }
#undef STAGEQ
#undef PHASE

#pragma unroll
  for (int i = 0; i < 8; ++i) {
    const int r0 = m0 + wm + i * 16 + quad * 4;
#pragma unroll
    for (int j = 0; j < 4; ++j) {
      const int cc = n0 + wn + j * 16 + col;
#pragma unroll
      for (int r = 0; r < 4; ++r)
        if (r0 + r < Mrows) C[(size_t)(r0 + r) * 512 + cc] = acc[i][j][r];
    }
  }
}

// ---------------- attention GEMM (N=128) with fused tanh-dot scorer ----------------
// computes t = h@Wa1 per 128x128 tile, then s[m] = sum_c tanh(t[m][c]+ba1[c])*Wa2[c] + ba2
__global__ __launch_bounds__(256) void mfma_att_kernel(
    const ushort_t* __restrict__ Ah, const ushort_t* __restrict__ Al,
    const ushort_t* __restrict__ Bh, const ushort_t* __restrict__ Bl,
    const float* __restrict__ ba1, const float* __restrict__ Wa2,
    const float* __restrict__ ba2, float* __restrict__ S, int Mrows, int Kpad) {
  __shared__ ushort_t lAh[128 * 32];
  __shared__ ushort_t lAl[128 * 32];
  __shared__ ushort_t lBh[128 * 32];
  __shared__ ushort_t lBl[128 * 32];
  __shared__ float sat[128][2];
  const int tid = threadIdx.x;
  const int m0 = blockIdx.y * 128;
  const int w = tid >> 6, lane = tid & 63;
  const int wm = (w >> 1) * 64, wn = (w & 1) * 64;
  const int col = lane & 15, quad = lane >> 4;

  f32x4 acc[4][4];
#pragma unroll
  for (int i = 0; i < 4; ++i)
#pragma unroll
    for (int j = 0; j < 4; ++j) acc[i][j] = (f32x4)(0.f);

  for (int kt = 0; kt < Kpad; kt += 32) {
#pragma unroll
    for (int j = 0; j < 2; ++j) {
      const int ch = tid + j * 256;
      const int r = ch >> 2, c = ch & 3;
      const size_t goA = (size_t)(m0 + r) * Kpad + kt + c * 8;
      const size_t goB = (size_t)r * Kpad + kt + c * 8;
      GLDS(Ah + goA, &lAh[ch * 8]);
      GLDS(Al + goA, &lAl[ch * 8]);
      GLDS(Bh + goB, &lBh[ch * 8]);
      GLDS(Bl + goB, &lBl[ch * 8]);
    }
    __syncthreads();
    short8 ah[4], al[4], bh[4], bl[4];
#pragma unroll
    for (int i = 0; i < 4; ++i) {
      const int ar = wm + i * 16 + col;
      ah[i] = *(const short8*)&lAh[ar * 32 + quad * 8];
      al[i] = *(const short8*)&lAl[ar * 32 + quad * 8];
      const int br = wn + i * 16 + col;
      bh[i] = *(const short8*)&lBh[br * 32 + quad * 8];
      bl[i] = *(const short8*)&lBl[br * 32 + quad * 8];
    }
    __syncthreads();
#pragma unroll
    for (int i = 0; i < 4; ++i)
#pragma unroll
      for (int j = 0; j < 4; ++j) {
        acc[i][j] = __builtin_amdgcn_mfma_f32_16x16x32_bf16(ah[i], bh[j], acc[i][j], 0, 0, 0);
        acc[i][j] = __builtin_amdgcn_mfma_f32_16x16x32_bf16(ah[i], bl[j], acc[i][j], 0, 0, 0);
        acc[i][j] = __builtin_amdgcn_mfma_f32_16x16x32_bf16(al[i], bh[j], acc[i][j], 0, 0, 0);
      }
  }
  // epilogue: per-row tanh-dot
  float part[4][4];
#pragma unroll
  for (int i = 0; i < 4; ++i)
#pragma unroll
    for (int r = 0; r < 4; ++r) part[i][r] = 0.f;
#pragma unroll
  for (int j = 0; j < 4; ++j) {
    const int cc = wn + j * 16 + col;
    const float a1 = ba1[cc];
    const float w2 = Wa2[cc];
#pragma unroll
    for (int i = 0; i < 4; ++i)
#pragma unroll
      for (int r = 0; r < 4; ++r)
        part[i][r] += tanhf(acc[i][j][r] + a1) * w2;
  }
#pragma unroll
  for (int mask = 1; mask < 16; mask <<= 1)
#pragma unroll
    for (int i = 0; i < 4; ++i)
#pragma unroll
      for (int r = 0; r < 4; ++r) part[i][r] += __shfl_xor(part[i][r], mask, 64);
  if (col == 0) {
#pragma unroll
    for (int i = 0; i < 4; ++i)
#pragma unroll
      for (int r = 0; r < 4; ++r) sat[wm + i * 16 + quad * 4 + r][wn >> 6] = part[i][r];
  }
  __syncthreads();
  if (tid < 128) {
    const int gm = m0 + tid;
    if (gm < Mrows) S[gm] = sat[tid][0] + sat[tid][1] + ba2[0];
  }
}

// ---------------- conversions ----------------
__global__ __launch_bounds__(256) void convert_x_kernel(
    const float* __restrict__ x, int nrows,
    ushort_t* __restrict__ xh, ushort_t* __restrict__ xl, int K, int Kpad) {
  const int perRow = Kpad / 4;
  const int t = blockIdx.x * blockDim.x + threadIdx.x;
  if (t >= nrows * perRow) return;
  const int r = t / perRow, k0 = (t % perRow) * 4;
  const float* xr = x + (size_t)r * K;
  ushort_t h[4], l[4];
#pragma unroll
  for (int i = 0; i < 4; ++i) {
    const float v = (k0 + i < K) ? xr[k0 + i] : 0.f;
    split2(v, h[i], l[i]);
  }
  const size_t o = (size_t)r * Kpad + k0;
  *(ushort4*)(xh + o) = make_ushort4(h[0], h[1], h[2], h[3]);
  *(ushort4*)(xl + o) = make_ushort4(l[0], l[1], l[2], l[3]);
}

// fused transpose+split: rows n<256 from W1[k][n], n>=256 from W2[k][n-256]
__global__ void convert_wt_kernel(const float* __restrict__ W1, const float* __restrict__ W2,
                                  ushort_t* __restrict__ wth, ushort_t* __restrict__ wtl,
                                  int K, int Kpad, int ntot, int ld) {
  const int t = blockIdx.x * blockDim.x + threadIdx.x;
  if (t >= ntot * Kpad) return;
  const int n = t / Kpad, k = t % Kpad;
  float v = 0.f;
  if (k < K) v = (n < 256) ? W1[(size_t)k * ld + n] : W2[(size_t)k * ld + (n - 256)];
  ushort_t h, l;
  split2(v, h, l);
  wth[t] = h;
  wtl[t] = l;
}

// ---------------- CSR build ----------------
__global__ void deg_count_kernel(const int* __restrict__ dst, int* __restrict__ degi, int nE) {
  int e = blockIdx.x * blockDim.x + threadIdx.x;
  if (e < nE) atomicAdd(&degi[dst[e]], 1);
}

__global__ __launch_bounds__(1024) void scan_kernel(const int* __restrict__ degi,
                                                    int* __restrict__ rowptr, int M) {
  __shared__ int part[1024];
  const int t = threadIdx.x;
  const int chunk = (M + 1023) / 1024;
  const int b0 = min(t * chunk, M);
  const int b1 = min(b0 + chunk, M);
  int s = 0;
  for (int i = b0; i < b1; ++i) s += degi[i];
  part[t] = s;
  __syncthreads();
  for (int off = 1; off < 1024; off <<= 1) {
    int v = (t >= off) ? part[t - off] : 0;
    __syncthreads();
    part[t] += v;
    __syncthreads();
  }
  int ex = (t == 0) ? 0 : part[t - 1];
  for (int i = b0; i < b1; ++i) {
    rowptr[i] = ex;
    ex += degi[i];
  }
  if (t == 1023) rowptr[M] = part[1023];
}

__global__ void fill_kernel(const int* __restrict__ src, const int* __restrict__ dst,
                            int* __restrict__ fill, const int* __restrict__ rowptr,
                            int* __restrict__ csr_src, int nE) {
  int e = blockIdx.x * blockDim.x + threadIdx.x;
  if (e >= nE) return;
  const int d = dst[e];
  const int pos = rowptr[d] + atomicAdd(&fill[d], 1);
  csr_src[pos] = src[e];
}

// ---------------- fused gather-mean + bias + hr + BN stats ----------------
// gbuf: [M][512] (cols 0-255 = hl, 256-511 = hr)
#define GNB 64
__global__ __launch_bounds__(256) void gather_combine_kernel(
    const float* __restrict__ gbuf,
    const int* __restrict__ rowptr, const int* __restrict__ csr_src,
    const float* __restrict__ bl, float* preBN,
    float* __restrict__ bsum, float* __restrict__ bsumsq, int M) {
  __shared__ float lsum[4][HID];
  __shared__ float lsq[4][HID];
  const int w = threadIdx.x >> 6;
  const int lane = threadIdx.x & 63;
  const float4 blv = ((const float4*)bl)[lane];
  float4 s = make_float4(0.f, 0.f, 0.f, 0.f);
  float4 q = make_float4(0.f, 0.f, 0.f, 0.f);
  const int base = blockIdx.x * GNB;
  for (int it = 0; it < GNB / 4; ++it) {
    const int n = base + it * 4 + w;
    if (n < M) {
      const int e0 = rowptr[n], e1 = rowptr[n + 1];
      float4 acc = make_float4(0.f, 0.f, 0.f, 0.f);
      float4 acc2 = make_float4(0.f, 0.f, 0.f, 0.f);
      int e = e0;
      // 2-edge unroll: two independent gather rows in flight (latency-bound)
      for (; e + 2 <= e1; e += 2) {
        const int sn0 = csr_src[e];
        const int sn1 = csr_src[e + 1];
        const float4 v0 = ((const float4*)(gbuf + (size_t)sn0 * 512))[lane];
        const float4 v1 = ((const float4*)(gbuf + (size_t)sn1 * 512))[lane];
        acc.x += v0.x; acc.y += v0.y; acc.z += v0.z; acc.w += v0.w;
        acc2.x += v1.x; acc2.y += v1.y; acc2.z += v1.z; acc2.w += v1.w;
      }
      if (e < e1) {
        const int sn = csr_src[e];
        const float4 v = ((const float4*)(gbuf + (size_t)sn * 512))[lane];
        acc.x += v.x; acc.y += v.y; acc.z += v.z; acc.w += v.w;
      }
      acc.x += acc2.x; acc.y += acc2.y; acc.z += acc2.z; acc.w += acc2.w;
      const float rd = 1.0f / fmaxf((float)(e1 - e0), 1.0f);
      const float4 hv = ((const float4*)(gbuf + (size_t)n * 512 + 256))[lane];
      float4 o;
      o.x = fmaf(acc.x, rd, blv.x + hv.x);
      o.y = fmaf(acc.y, rd, blv.y + hv.y);
      o.z = fmaf(acc.z, rd, blv.z + hv.z);
      o.w = fmaf(acc.w, rd, blv.w + hv.w);
      ((float4*)(preBN + (size_t)n * HID))[lane] = o;
      s.x += o.x; s.y += o.y; s.z += o.z; s.w += o.w;
      q.x = fmaf(o.x, o.x, q.x); q.y = fmaf(o.y, o.y, q.y);
      q.z = fmaf(o.z, o.z, q.z); q.w = fmaf(o.w, o.w, q.w);
    }
  }
  *(float4*)&lsum[w][lane * 4] = s;
  *(float4*)&lsq[w][lane * 4] = q;
  __syncthreads();
  const int c = threadIdx.x;
  const float ts = lsum[0][c] + lsum[1][c] + lsum[2][c] + lsum[3][c];
  const float tq = lsq[0][c] + lsq[1][c] + lsq[2][c] + lsq[3][c];
  atomicAdd(&bsum[c], ts);
  atomicAdd(&bsumsq[c], tq);
}

// BN(scale/shift recomputed per block) + ReLU -> bf16 split (+ optional fp32)
__global__ __launch_bounds__(256) void bn_apply_relu_convert_kernel(
    const float* __restrict__ preBN, const float* __restrict__ bsum,
    const float* __restrict__ bsumsq, const float* __restrict__ g, const float* __restrict__ b,
    ushort_t* __restrict__ hh, ushort_t* __restrict__ hl, float* __restrict__ hout,
    int M, int n4) {
  __shared__ float s_sc[HID], s_sh[HID];
  {
    const int c = threadIdx.x;
    const float inv = 1.0f / (float)M;
    const float mean = bsum[c] * inv;
    const float var = bsumsq[c] * inv - mean * mean;
    const float sc = g[c] * rsqrtf(var + 1e-5f);
    s_sc[c] = sc;
    s_sh[c] = b[c] - mean * sc;
  }
  __syncthreads();
  const int i = blockIdx.x * blockDim.x + threadIdx.x;
  if (i >= n4) return;
  const int c0 = (i & (HID / 4 - 1)) * 4;
  const float4 v = ((const float4*)preBN)[i];
  float o[4];
  o[0] = fmaxf(fmaf(v.x, s_sc[c0 + 0], s_sh[c0 + 0]), 0.f);
  o[1] = fmaxf(fmaf(v.y, s_sc[c0 + 1], s_sh[c0 + 1]), 0.f);
  o[2] = fmaxf(fmaf(v.z, s_sc[c0 + 2], s_sh[c0 + 2]), 0.f);
  o[3] = fmaxf(fmaf(v.w, s_sc[c0 + 3], s_sh[c0 + 3]), 0.f);
  ushort_t h[4], l[4];
#pragma unroll
  for (int k = 0; k < 4; ++k) split2(o[k], h[k], l[k]);
  ((ushort4*)hh)[i] = make_ushort4(h[0], h[1], h[2], h[3]);
  ((ushort4*)hl)[i] = make_ushort4(l[0], l[1], l[2], l[3]);
  if (hout) ((float4*)hout)[i] = make_float4(o[0], o[1], o[2], o[3]);
}

// ---------------- softmax over graphs ----------------
__device__ __forceinline__ unsigned fflip(float f) {
  unsigned u = __float_as_uint(f);
  return (u & 0x80000000u) ? ~u : (u | 0x80000000u);
}
__device__ __forceinline__ float funflip(unsigned u) {
  return __uint_as_float((u & 0x80000000u) ? (u ^ 0x80000000u) : ~u);
}

__global__ void seg_max_kernel(const float* __restrict__ s, const int* __restrict__ batch,
                               unsigned* __restrict__ gmax, int M) {
  __shared__ unsigned lmax[NGRAPH];
  if (threadIdx.x < NGRAPH) lmax[threadIdx.x] = 0u;
  __syncthreads();
  for (int i = blockIdx.x * blockDim.x + threadIdx.x; i < M; i += gridDim.x * blockDim.x)
    atomicMax(&lmax[batch[i]], fflip(s[i]));
  __syncthreads();
  if (threadIdx.x < NGRAPH && lmax[threadIdx.x] != 0u) atomicMax(&gmax[threadIdx.x], lmax[threadIdx.x]);
}

__global__ void seg_expsum_kernel(const float* __restrict__ s, const int* __restrict__ batch,
                                  const unsigned* __restrict__ gmax, float* __restrict__ e,
                                  float* __restrict__ denom, int M) {
  __shared__ float ld[NGRAPH];
  if (threadIdx.x < NGRAPH) ld[threadIdx.x] = 0.f;
  __syncthreads();
  for (int i = blockIdx.x * blockDim.x + threadIdx.x; i < M; i += gridDim.x * blockDim.x) {
    const int b = batch[i];
    const float v = expf(s[i] - funflip(gmax[b]));
    e[i] = v;
    atomicAdd(&ld[b], v);
  }
  __syncthreads();
  if (threadIdx.x < NGRAPH && ld[threadIdx.x] != 0.f) atomicAdd(&denom[threadIdx.x], ld[threadIdx.x]);
}

#define PNB 16
__global__ __launch_bounds__(256) void pool_kernel(
    const float* __restrict__ h, const float* __restrict__ e, const float* __restrict__ denom,
    const int* __restrict__ batch, float* __restrict__ pooled, int M) {
  const int wid = (blockIdx.x * blockDim.x + threadIdx.x) >> 6;
  const int lane = threadIdx.x & 63;
  const int n0 = wid * PNB;
  if (n0 >= M) return;
  const int n1 = min(n0 + PNB, M);
  float4 acc = make_float4(0.f, 0.f, 0.f, 0.f);
  int cur = batch[n0];
  for (int n = n0; n < n1; ++n) {
    const int b = batch[n];
    if (b != cur) {
      float* o = pooled + (size_t)cur * HID + lane * 4;
      atomicAdd(o + 0, acc.x); atomicAdd(o + 1, acc.y);
      atomicAdd(o + 2, acc.z); atomicAdd(o + 3, acc.w);
      acc = make_float4(0.f, 0.f, 0.f, 0.f);
      cur = b;
    }
    const float w = e[n] / denom[b];
    const float4 v = ((const float4*)(h + (size_t)n * HID))[lane];
    acc.x = fmaf(v.x, w, acc.x); acc.y = fmaf(v.y, w, acc.y);
    acc.z = fmaf(v.z, w, acc.z); acc.w = fmaf(v.w, w, acc.w);
  }
  float* o = pooled + (size_t)cur * HID + lane * 4;
  atomicAdd(o + 0, acc.x); atomicAdd(o + 1, acc.y);
  atomicAdd(o + 2, acc.z); atomicAdd(o + 3, acc.w);
}

__global__ __launch_bounds__(128) void classifier_kernel(
    const float* __restrict__ pooled, const float* __restrict__ Wc1, const float* __restrict__ bc1,
    const float* __restrict__ Wc2, const float* __restrict__ bc2, float* __restrict__ out) {
  __shared__ float red[128];
  const int g = blockIdx.x;
  const int j = threadIdx.x;
  float acc = bc1[j];
  const float* p = pooled + (size_t)g * HID;
  for (int c = 0; c < HID; ++c) acc = fmaf(p[c], Wc1[c * 128 + j], acc);
  red[j] = fmaxf(acc, 0.f) * Wc2[j];
  __syncthreads();
  for (int off = 64; off > 0; off >>= 1) {
    if (j < off) red[j] += red[j + off];
    __syncthreads();
  }
  if (j == 0) out[g] = red[0] + bc2[0];
}

extern "C" void kernel_launch(void* const* d_in, const int* in_sizes, int n_in,
                              void* d_out, int out_size, void* d_ws, size_t ws_size,
                              hipStream_t stream) {
  const float* x = (const float*)d_in[0];
  const int* edge = (const int*)d_in[1];
  const int* batch = (const int*)d_in[2];
  const int M = in_sizes[2];
  const int nE = in_sizes[1] / 2;
  const int IN_DIM = in_sizes[0] / M;  // 771
  const int* src = edge;
  const int* dst = edge + nE;

  const int Mpad = ((M + 255) / 256) * 256;  // 256-tile GEMM padding
  const int KP0 = ((IN_DIM + 31) / 32) * 32;  // 800
  const int mblocks = (M + 127) / 128;        // att kernel tiles
  const int mb256 = (M + 255) / 256;          // gemm512 tiles

  float* ws = (float*)d_ws;
  float* gbuf = ws;                                    // [M][512]
  float* pbuf = gbuf + (size_t)M * 512;                // [M][256]
  float* h32 = pbuf + (size_t)M * HID;                 // [M][256]
  float* ssc = h32 + (size_t)M * HID;                  // M
  float* ew = ssc + M;                                 // M
  float* bsumA = ew + M;                               // 3 layers x (256 sum + 256 sq)
  unsigned* gmax = (unsigned*)(bsumA + 6 * HID);       // 64
  float* denom = (float*)(gmax + NGRAPH);              // 64
  float* pooled = denom + NGRAPH;                      // 64*256
  int* degi = (int*)(pooled + (size_t)NGRAPH * HID);   // M
  int* filla = degi + M;                               // M
  int* rowptr = filla + M;                             // M+1
  int* csr_src = rowptr + M + 1;                       // nE

  ushort_t* wp = (ushort_t*)(((uintptr_t)(csr_src + nE) + 15) & ~(uintptr_t)15);
  ushort_t* w0h = wp;                 ushort_t* w0l = w0h + (size_t)512 * KP0;
  ushort_t* w1h = w0l + (size_t)512 * KP0;  ushort_t* w1l = w1h + (size_t)512 * HID;
  ushort_t* w2h = w1l + (size_t)512 * HID;  ushort_t* w2l = w2h + (size_t)512 * HID;
  ushort_t* wah = w2l + (size_t)512 * HID;  ushort_t* wal = wah + (size_t)128 * HID;
  ushort_t* cvh = (ushort_t*)(((uintptr_t)(wal + (size_t)128 * HID) + 15) & ~(uintptr_t)15);
  ushort_t* cvl = cvh + (size_t)Mpad * KP0;

  // ---- CSR build ----
  hipMemsetAsync(degi, 0, (size_t)(2 * M) * sizeof(int), stream);
  deg_count_kernel<<<(nE + 255) / 256, 256, 0, stream>>>(dst, degi, nE);
  scan_kernel<<<1, 1024, 0, stream>>>(degi, rowptr, M);
  fill_kernel<<<(nE + 255) / 256, 256, 0, stream>>>(src, dst, filla, rowptr, csr_src, nE);
  // one memset for all small accumulators: bsumA(1536) + gmax(64) + denom(64) + pooled(16384)
  hipMemsetAsync(bsumA, 0, (size_t)(6 * HID + 2 * NGRAPH + NGRAPH * HID) * 4, stream);

  // ---- weight transpose + split (fused Wl||Wr per layer) ----
  {
    const int nt0 = 512 * KP0;
    convert_wt_kernel<<<(nt0 + 255) / 256, 256, 0, stream>>>(
        (const float*)d_in[3], (const float*)d_in[5], w0h, w0l, IN_DIM, KP0, 512, HID);
    const int nt1 = 512 * HID;
    convert_wt_kernel<<<(nt1 + 255) / 256, 256, 0, stream>>>(
        (const float*)d_in[8], (const float*)d_in[10], w1h, w1l, HID, HID, 512, HID);
    convert_wt_kernel<<<(nt1 + 255) / 256, 256, 0, stream>>>(
        (const float*)d_in[13], (const float*)d_in[15], w2h, w2l, HID, HID, 512, HID);
    convert_wt_kernel<<<(128 * HID + 255) / 256, 256, 0, stream>>>(
        (const float*)d_in[18], nullptr, wah, wal, HID, HID, 128, 128);
  }

  // layer-0 input split (+ zero the 256-pad tail rows for the KP0-stride layout)
  {
    const int nt = M * (KP0 / 4);
    convert_x_kernel<<<(nt + 255) / 256, 256, 0, stream>>>(x, M, cvh, cvl, IN_DIM, KP0);
    if (Mpad > M) {
      hipMemsetAsync(cvh + (size_t)M * KP0, 0, (size_t)(Mpad - M) * KP0 * 2, stream);
      hipMemsetAsync(cvl + (size_t)M * KP0, 0, (size_t)(Mpad - M) * KP0 * 2, stream);
    }
  }

  const int n4 = (int)((size_t)M * HID / 4);
  const ushort_t* WH[3] = {w0h, w1h, w2h};
  const ushort_t* WL[3] = {w0l, w1l, w2l};
  for (int l = 0; l < 3; ++l) {
    const int KP = (l == 0) ? KP0 : HID;
    const float* bl = (const float*)d_in[3 + l * 5 + 1];
    const float* gg = (const float*)d_in[3 + l * 5 + 3];
    const float* bb = (const float*)d_in[3 + l * 5 + 4];
    float* bsum = bsumA + l * 512;
    float* bsumsq = bsum + HID;

    dim3 g(2, mb256);
    mfma_gemm512_kernel<<<g, 512, 0, stream>>>(cvh, cvl, WH[l], WL[l], gbuf, M, KP);
    gather_combine_kernel<<<(M + GNB - 1) / GNB, 256, 0, stream>>>(
        gbuf, rowptr, csr_src, bl, pbuf, bsum, bsumsq, M);
    // overwrite cvh/cvl with next layer's split ([Mpad][256] fits in [Mpad][800] region)
    bn_apply_relu_convert_kernel<<<(n4 + 255) / 256, 256, 0, stream>>>(
        pbuf, bsum, bsumsq, gg, bb, cvh, cvl, (l == 2) ? h32 : nullptr, M, n4);
    if (l == 0 && Mpad > M) {
      // zero the pad tail once for the HID-stride layout (layers 1,2 + att)
      hipMemsetAsync(cvh + (size_t)M * HID, 0, (size_t)(Mpad - M) * HID * 2, stream);
      hipMemsetAsync(cvl + (size_t)M * HID, 0, (size_t)(Mpad - M) * HID * 2, stream);
    }
  }

  // attention scores (GEMM + fused tanh-dot epilogue)
  {
    dim3 g(1, mblocks);
    mfma_att_kernel<<<g, 256, 0, stream>>>(
        cvh, cvl, wah, wal, (const float*)d_in[19], (const float*)d_in[20],
        (const float*)d_in[21], ssc, M, HID);
  }
  seg_max_kernel<<<512, 256, 0, stream>>>(ssc, batch, gmax, M);
  seg_expsum_kernel<<<512, 256, 0, stream>>>(ssc, batch, gmax, ew, denom, M);
  {
    const int nwaves = (M + PNB - 1) / PNB;
    pool_kernel<<<(nwaves * 64 + 255) / 256, 256, 0, stream>>>(h32, ew, denom, batch, pooled, M);
  }
  classifier_kernel<<<NGRAPH, 128, 0, stream>>>(
      pooled, (const float*)d_in[22], (const float*)d_in[23],
      (const float*)d_in[24], (const float*)d_in[25], (float*)d_out);
}